// Round 4
// baseline (359.477 us; speedup 1.0000x reference)
//
#include <hip/hip_runtime.h>
#include <math.h>

#define B_    4
#define K_    2048
#define D_    1024
#define H_    16
#define NCTX_ 1024

typedef unsigned short ushort_t;
typedef _Float16 f16;
typedef __attribute__((ext_vector_type(8))) _Float16 f16x8;
typedef __attribute__((ext_vector_type(4))) float f32x4;

union U4 {
  f16 h[4];
  ushort4 u;
};

__device__ __forceinline__ void gload16(const void* g, void* l) {
  __builtin_amdgcn_global_load_lds(
      (const __attribute__((address_space(1))) unsigned int*)g,
      (__attribute__((address_space(3))) unsigned int*)l, 16, 0, 0);
}

// ---------------------------------------------------------------------------
// Kernel 1: partition scan (verified R1-R4).
// ---------------------------------------------------------------------------
__global__ __launch_bounds__(256) void partition_kernel(
    const unsigned char* __restrict__ isctx, int* __restrict__ pos,
    int* __restrict__ ipos) {
  const int b = blockIdx.x;
  const int tid = threadIdx.x;
  const int wid = tid >> 6, lane = tid & 63;
  __shared__ int csum[4];
  __shared__ int waveTot[4];
  __shared__ int strideSh;

  int cnt = 0;
  for (int i = 0; i < 32; ++i) cnt += (isctx[tid * 32 + i] != 0);
  for (int off = 32; off; off >>= 1) cnt += __shfl_down(cnt, off, 64);
  if (lane == 0) csum[wid] = cnt;
  __syncthreads();
  if (tid == 0) {
    int t = csum[0] + csum[1] + csum[2] + csum[3];
    strideSh = (t > 2048) ? 1 : ((t > 768) ? 4 : 8);
  }
  __syncthreads();
  const int stride = strideSh;

  const unsigned char* base = isctx + (size_t)b * K_ * stride;
  int f[8];
  int s = 0;
  for (int i = 0; i < 8; ++i) {
    f[i] = base[(size_t)(tid * 8 + i) * stride] != 0;
    s += f[i];
  }
  int inc = s;
  for (int off = 1; off < 64; off <<= 1) {
    int v = __shfl_up(inc, off, 64);
    if (lane >= off) inc += v;
  }
  if (lane == 63) waveTot[wid] = inc;
  __syncthreads();
  int wOff = 0;
  for (int w = 0; w < wid; ++w) wOff += waveTot[w];
  int run = wOff + inc - s;
  for (int i = 0; i < 8; ++i) {
    int k = tid * 8 + i;
    int p;
    if (f[i]) {
      p = run;
      run++;
    } else {
      p = NCTX_ + k - run;
    }
    pos[b * K_ + k] = p;
    ipos[b * K_ + p] = k;
  }
}

// ---------------------------------------------------------------------------
// Kernel 2: RoPE + permute-gather -> f16 token buffer.
// ---------------------------------------------------------------------------
__global__ __launch_bounds__(256) void rope_kernel(
    const float* __restrict__ x, const float* __restrict__ coords,
    const float* __restrict__ cache, const int* __restrict__ ipos,
    f16* __restrict__ tok) {
  const int row = blockIdx.x;
  const int b = row >> 11;
  const int r = row & (K_ - 1);
  const int k = ipos[row];
  const int t = threadIdx.x;

  const float cy = coords[(size_t)(b * K_ + k) * 2 + 0];
  const float cx = coords[(size_t)(b * K_ + k) * 2 + 1];
  const int ypos = (int)fminf(fmaxf(cy / 224.0f * 1023.0f, 0.0f), 1023.0f);
  const int xpos = (int)fminf(fmaxf(cx / 224.0f * 1023.0f, 0.0f), 1023.0f);

  const float4 v = ((const float4*)(x + ((size_t)b * K_ + k) * D_))[t];
  const int e = 4 * t;
  const float* crow;
  int coff;
  if (e < 512) {
    crow = cache + (size_t)xpos * 512;
    coff = e;
  } else {
    crow = cache + (size_t)ypos * 512;
    coff = e - 512;
  }
  const float4 cs = *(const float4*)(crow + coff);
  float o[4];
  o[0] = v.x * cs.x - v.y * cs.y;
  o[1] = v.x * cs.y + v.y * cs.x;
  o[2] = v.z * cs.z - v.w * cs.w;
  o[3] = v.z * cs.w + v.w * cs.z;
  U4 h;
#pragma unroll
  for (int i = 0; i < 4; ++i) h.h[i] = (f16)o[i];
  ((ushort4*)(tok + ((size_t)b * K_ + r) * D_))[t] = h.u;
}

// ---------------------------------------------------------------------------
// Kernel 3: all weights fp32 -> f16, concatenated:
// [0,3M) ctx_in | [3M,5M) tgt_in kv | [5M,6M) tgt_in q | [6M,7M) ctx_out |
// [7M,8M) tgt_out   (M = 1048576 floats)
// ---------------------------------------------------------------------------
__global__ __launch_bounds__(256) void cvt_all(
    const float* __restrict__ ctx_in_w, const float* __restrict__ tgt_in_w,
    const float* __restrict__ ctx_out_w, const float* __restrict__ tgt_out_w,
    f16* __restrict__ dst) {
  const int i4 = blockIdx.x * 256 + threadIdx.x;  // 0..2097151
  const int f = i4 * 4;
  const float* src;
  if (f < 3145728) src = ctx_in_w + f;
  else if (f < 5242880) src = tgt_in_w + (f - 3145728 + 1048576);
  else if (f < 6291456) src = tgt_in_w + (f - 5242880);
  else if (f < 7340032) src = ctx_out_w + (f - 6291456);
  else src = tgt_out_w + (f - 7340032);
  const float4 v = *(const float4*)src;
  U4 u;
  u.h[0] = (f16)v.x;
  u.h[1] = (f16)v.y;
  u.h[2] = (f16)v.z;
  u.h[3] = (f16)v.w;
  ((ushort4*)dst)[i4] = u.u;
}

// ---------------------------------------------------------------------------
// GEMM core v3 (verified R3): coalesced staging (8-lane contiguous 128-B row
// segments), row-major [128][64] LDS with both-sides XOR swizzle, BK=64,
// double-buffered, counted vmcnt(8). gemm_proj 120 -> 75.8us, conflicts 0.
// ---------------------------------------------------------------------------
#define GEMM_PRE(AP, WP, Kd)                                                  \
  const int rb_ = wave * 8 + (lane >> 3);         /* row 0..31 (j adds 32) */ \
  const int kk_ = ((lane & 7) ^ (lane >> 3)) * 8; /* pre-swizzled k-chunk */  \
  const f16* gA_ = (AP) + (size_t)rb_ * (Kd) + kk_;                           \
  const f16* gW_ = (WP) + (size_t)rb_ * (Kd) + kk_;                           \
  const int lA_ = wave * 8 * 64 + lane * 8; /* == row*64 + kkchunk*8 */

#define GEMM_STAGE(k0s, bb)                                                   \
  _Pragma("unroll") for (int j = 0; j < 4; ++j) {                             \
    gload16(gA_ + (size_t)j * 32 * Kd_ + (k0s), &lds[(bb) + j * 2048 + lA_]); \
    gload16(gW_ + (size_t)j * 32 * Kd_ + (k0s),                               \
            &lds[(bb) + 8192 + j * 2048 + lA_]);                              \
  }

#define GEMM_TILE(bb)                                                         \
  _Pragma("unroll") for (int kh = 0; kh < 2; ++kh) {                          \
    f16x8 af[4], wf[4];                                                       \
    _Pragma("unroll") for (int i = 0; i < 4; ++i) {                           \
      const int ca = ((kh * 4 + quad) ^ (m16 & 7)) * 8;                       \
      af[i] = *(const f16x8*)&lds[(bb) + (wm + i * 16 + m16) * 64 + ca];      \
      wf[i] =                                                                 \
          *(const f16x8*)&lds[(bb) + 8192 + (wn + i * 16 + m16) * 64 + ca];   \
    }                                                                         \
    _Pragma("unroll") for (int i = 0; i < 4; ++i)                             \
        _Pragma("unroll") for (int j = 0; j < 4; ++j)                         \
      acc[i][j] = __builtin_amdgcn_mfma_f32_16x16x32_f16(af[i], wf[j],        \
                                                         acc[i][j], 0, 0, 0); \
  }

#define GEMM_CORE(AP, WP, Kd)                                                 \
  f32x4 acc[4][4];                                                            \
  {                                                                           \
    const f32x4 z = {0.f, 0.f, 0.f, 0.f};                                     \
    for (int i = 0; i < 4; ++i)                                               \
      for (int j = 0; j < 4; ++j) acc[i][j] = z;                              \
  }                                                                           \
  const int Kd_ = (Kd);                                                       \
  GEMM_PRE(AP, WP, Kd_)                                                       \
  GEMM_STAGE(0, 0)                                                            \
  for (int t = 0; t < Kd_ / 64; ++t) {                                        \
    const int cb = (t & 1) * 16384;                                           \
    if (t + 1 < Kd_ / 64) {                                                   \
      GEMM_STAGE((t + 1) * 64, ((t + 1) & 1) * 16384)                         \
      asm volatile("s_waitcnt vmcnt(8)" ::: "memory");                        \
    } else {                                                                  \
      asm volatile("s_waitcnt vmcnt(0)" ::: "memory");                        \
    }                                                                         \
    __builtin_amdgcn_s_barrier();                                             \
    asm volatile("" ::: "memory");                                            \
    GEMM_TILE(cb)                                                             \
    asm volatile("" ::: "memory");                                            \
    __builtin_amdgcn_s_barrier();                                             \
  }

// ---------------------------------------------------------------------------
// Kernel 4: merged projection GEMM. grid (48, 8, 4):
//   nb < 40: ctx rows x [ctx_in QKV (3072) | tgt_in KV (2048)] -> qkvc / kvt
//   nb >= 40: tgt rows x tgt_in Q (1024) -> qt
// ---------------------------------------------------------------------------
__global__ __launch_bounds__(256, 2) void gemm_proj(
    const f16* __restrict__ tok, const f16* __restrict__ wcat,
    const float* __restrict__ ctx_in_b, const float* __restrict__ tgt_in_b,
    f16* __restrict__ qkvc, f16* __restrict__ kvt, f16* __restrict__ qt) {
  __shared__ f16 lds[32768];
  const int tid = threadIdx.x;
  const int wave = tid >> 6, lane = tid & 63;
  const int quad = lane >> 4, m16 = lane & 15;
  const int nb = blockIdx.x, mb = blockIdx.y, b = blockIdx.z;
  const int wm = (wave & 1) << 6, wn = (wave >> 1) << 6;
  const int m0 = mb * 128;
  const bool isQ = nb >= 40;
  const int n0 = isQ ? (nb - 40) * 128 : nb * 128;
  const f16* AP = tok + (size_t)b * K_ * D_ +
                  (isQ ? (size_t)NCTX_ * D_ : (size_t)0) + (size_t)m0 * D_;
  const f16* WP = wcat + (isQ ? (size_t)5242880 : (size_t)0) +
                  (size_t)n0 * D_;

  GEMM_CORE(AP, WP, D_)

#pragma unroll
  for (int j = 0; j < 4; ++j) {
    const int col = n0 + wn + j * 16 + m16;
    float bv;
    f16* dst;
    int ldc, dcol;
    if (isQ) {
      bv = tgt_in_b[col];
      dst = qt + (size_t)b * NCTX_ * D_;
      ldc = D_;
      dcol = col;
    } else if (col < 3072) {
      bv = ctx_in_b[col];
      dst = qkvc + (size_t)b * NCTX_ * 3072;
      ldc = 3072;
      dcol = col;
    } else {
      bv = tgt_in_b[D_ + col - 3072];
      dst = kvt + (size_t)b * NCTX_ * 2048;
      ldc = 2048;
      dcol = col - 3072;
    }
#pragma unroll
    for (int i = 0; i < 4; ++i) {
      const int mr = m0 + wm + i * 16 + quad * 4;
#pragma unroll
      for (int r = 0; r < 4; ++r)
        dst[(size_t)(mr + r) * ldc + dcol] = (f16)(acc[i][j][r] + bv);
    }
  }
}

// ---------------------------------------------------------------------------
// Kernel 5: merged output projections. grid (8, 8, 8): b = z&3, sel = z>>2.
// fp32 output scattered to original token order (16-lane 64B segments ->
// already fully coalesced).
// ---------------------------------------------------------------------------
__global__ __launch_bounds__(256, 2) void gemm_out(
    const f16* __restrict__ Atok, const f16* __restrict__ Wbase,
    const float* __restrict__ bias_ctx, const float* __restrict__ bias_tgt,
    const int* __restrict__ ipos, float* __restrict__ out) {
  __shared__ f16 lds[32768];
  const int tid = threadIdx.x;
  const int wave = tid >> 6, lane = tid & 63;
  const int quad = lane >> 4, m16 = lane & 15;
  const int n0 = blockIdx.x * 128, m0 = blockIdx.y * 128;
  const int b = blockIdx.z & 3, sel = blockIdx.z >> 2;
  const int wm = (wave & 1) << 6, wn = (wave >> 1) << 6;
  const f16* AP = Atok + (size_t)b * K_ * D_ + (size_t)sel * NCTX_ * D_ +
                  (size_t)m0 * D_;
  const f16* WP = Wbase + (size_t)sel * 1048576 + (size_t)n0 * D_;
  const float* bias = sel ? bias_tgt : bias_ctx;

  GEMM_CORE(AP, WP, D_)

#pragma unroll
  for (int j = 0; j < 4; ++j) {
    const int col = n0 + wn + j * 16 + m16;
    const float bv = bias[col];
#pragma unroll
    for (int i = 0; i < 4; ++i) {
      const int mr = m0 + wm + i * 16 + quad * 4;
#pragma unroll
      for (int r = 0; r < 4; ++r) {
        const int orow = ipos[b * K_ + sel * NCTX_ + mr + r];
        out[(size_t)b * K_ * D_ + (size_t)orow * D_ + col] =
            acc[i][j][r] + bv;
      }
    }
  }
}

// ---------------------------------------------------------------------------
// Kernel 6: V transpose (16-bit moves).
// ---------------------------------------------------------------------------
__global__ __launch_bounds__(256) void vtrans_kernel(
    const ushort_t* __restrict__ V, long long sVb, int ldv, int coloff,
    ushort_t* __restrict__ Vt) {
  __shared__ __align__(16) ushort_t tile[64][72];
  const int tblk = blockIdx.x, h = blockIdx.y, b = blockIdx.z;
  const int tid = threadIdx.x;
  const ushort_t* src =
      V + (long long)b * sVb + (size_t)(tblk * 64) * ldv + coloff + h * 64;
#pragma unroll
  for (int j = 0; j < 2; ++j) {
    const int c = j * 256 + tid;
    const int r = c >> 3, dc = c & 7;
    *(uint4*)&tile[r][dc * 8] = *(const uint4*)(src + (size_t)r * ldv + dc * 8);
  }
  __syncthreads();
  ushort_t* dst = Vt + (size_t)(b * H_ + h) * 64 * 1024 + tblk * 64;
#pragma unroll
  for (int j = 0; j < 2; ++j) {
    const int c = j * 256 + tid;
    const int d = c >> 3, tc = c & 7;
    union {
      ushort_t u[8];
      uint4 v;
    } t;
#pragma unroll
    for (int i = 0; i < 8; ++i) t.u[i] = tile[tc * 8 + i][d];
    *(uint4*)(dst + (size_t)d * 1024 + tc * 8) = t.v;
  }
}

// ---------------------------------------------------------------------------
// Kernel 7: MFMA flash attention v2 — the R3 GEMM package applied to K/V/Q
// staging: 8-lane coalesced 128-B row segments (8x fewer VMEM requests),
// row-major [64][64] LDS tiles with both-sides XOR swizzle, K/V double
// buffer, counted vmcnt(4) per kt (never 0 until tail), Q fragments hoisted.
// LDS: Q 8K + K 2x8K + V 2x8K + P 8K = 48 KB (grid caps residency at 4
// blocks/CU anyway). Softmax / P path / output unchanged.
// ---------------------------------------------------------------------------
__global__ __launch_bounds__(256) void attn_mfma(
    const f16* __restrict__ Qp, long long sQb, int ldq,
    const f16* __restrict__ Kp, long long sKb, int ldk,
    const f16* __restrict__ Vt, f16* __restrict__ O, long long sOb) {
  __shared__ f16 Qs[4096];
  __shared__ f16 Ks[2][4096];
  __shared__ f16 Vs[2][4096];
  __shared__ f16 Ps[4096];
  const int tid = threadIdx.x, wave = tid >> 6, lane = tid & 63;
  const int quad = lane >> 4, m16 = lane & 15;
  const int q0 = blockIdx.x * 64, h = blockIdx.y, b = blockIdx.z;
  const f16* Qb = Qp + (long long)b * sQb + h * 64;
  const f16* Kb = Kp + (long long)b * sKb + h * 64;
  const f16* Vb = Vt + (size_t)(b * H_ + h) * 64 * 1024;

  // Coalesced staging geometry: 8 lanes per row, contiguous 128-B segment.
  const int rL = lane >> 3;              // row-within-8 (= row & 7)
  const int kkc = ((lane & 7) ^ rL) * 8; // pre-swizzled source chunk (f16)
  const int lB = wave * 512 + lane * 8;  // linear LDS dest (f16), +2048 for j=1

  // Prologue: stage Q (2 loads) then K0/V0 (4 loads).
#pragma unroll
  for (int j = 0; j < 2; ++j) {
    const int row = j * 32 + wave * 8 + rL;
    gload16(Qb + (size_t)(q0 + row) * ldq + kkc, &Qs[j * 2048 + lB]);
  }
#pragma unroll
  for (int j = 0; j < 2; ++j) {
    const int row = j * 32 + wave * 8 + rL;
    gload16(Kb + (size_t)row * ldk + kkc, &Ks[0][j * 2048 + lB]);
    gload16(Vb + (size_t)row * 1024 + kkc, &Vs[0][j * 2048 + lB]);
  }

  float m_run[4], l_run[4];
#pragma unroll
  for (int r = 0; r < 4; ++r) {
    m_run[r] = -1e30f;
    l_run[r] = 0.f;
  }
  f32x4 Oa[4];
  const f32x4 z = {0.f, 0.f, 0.f, 0.f};
#pragma unroll
  for (int j = 0; j < 4; ++j) Oa[j] = z;

  // Wait own Q loads (oldest 2 of 6 outstanding), barrier -> all waves' Q in.
  asm volatile("s_waitcnt vmcnt(4)" ::: "memory");
  __builtin_amdgcn_s_barrier();

  // Hoisted Q fragments (swizzled read: chunk c stored at slot c^(row&7)).
  const int c0 = (quad ^ (m16 & 7)) * 8;
  const int c1 = ((quad + 4) ^ (m16 & 7)) * 8;
  const f16x8 qf0 = *(const f16x8*)&Qs[(wave * 16 + m16) * 64 + c0];
  const f16x8 qf1 = *(const f16x8*)&Qs[(wave * 16 + m16) * 64 + c1];

  for (int kt = 0; kt < 16; ++kt) {
    const int cur = kt & 1;
    if (kt < 15) {
      // Prefetch next K/V tile into the other buffer (4 loads).
#pragma unroll
      for (int j = 0; j < 2; ++j) {
        const int row = j * 32 + wave * 8 + rL;
        gload16(Kb + (size_t)((kt + 1) * 64 + row) * ldk + kkc,
                &Ks[cur ^ 1][j * 2048 + lB]);
        gload16(Vb + (size_t)row * 1024 + (kt + 1) * 64 + kkc,
                &Vs[cur ^ 1][j * 2048 + lB]);
      }
      asm volatile("s_waitcnt vmcnt(4)" ::: "memory");  // tile kt landed
    } else {
      asm volatile("s_waitcnt vmcnt(0)" ::: "memory");
    }
    __builtin_amdgcn_s_barrier();

    f32x4 S[4];
#pragma unroll
    for (int jn = 0; jn < 4; ++jn) {
      S[jn] = z;
      const f16x8 kf0 = *(const f16x8*)&Ks[cur][(jn * 16 + m16) * 64 + c0];
      const f16x8 kf1 = *(const f16x8*)&Ks[cur][(jn * 16 + m16) * 64 + c1];
      S[jn] = __builtin_amdgcn_mfma_f32_16x16x32_f16(qf0, kf0, S[jn], 0, 0, 0);
      S[jn] = __builtin_amdgcn_mfma_f32_16x16x32_f16(qf1, kf1, S[jn], 0, 0, 0);
    }
#pragma unroll
    for (int jn = 0; jn < 4; ++jn) S[jn] *= 0.125f;
    float mnew[4], al[4], rs[4];
#pragma unroll
    for (int r = 0; r < 4; ++r) {
      float mx = fmaxf(fmaxf(S[0][r], S[1][r]), fmaxf(S[2][r], S[3][r]));
      mx = fmaxf(mx, __shfl_xor(mx, 1, 64));
      mx = fmaxf(mx, __shfl_xor(mx, 2, 64));
      mx = fmaxf(mx, __shfl_xor(mx, 4, 64));
      mx = fmaxf(mx, __shfl_xor(mx, 8, 64));
      mnew[r] = fmaxf(m_run[r], mx);
      al[r] = __expf(m_run[r] - mnew[r]);
      m_run[r] = mnew[r];
      rs[r] = 0.f;
    }
#pragma unroll
    for (int jn = 0; jn < 4; ++jn)
#pragma unroll
      for (int r = 0; r < 4; ++r) {
        const float p = __expf(S[jn][r] - mnew[r]);
        S[jn][r] = p;
        rs[r] += p;
      }
#pragma unroll
    for (int r = 0; r < 4; ++r) {
      float s = rs[r];
      s += __shfl_xor(s, 1, 64);
      s += __shfl_xor(s, 2, 64);
      s += __shfl_xor(s, 4, 64);
      s += __shfl_xor(s, 8, 64);
      l_run[r] = l_run[r] * al[r] + s;
    }
#pragma unroll
    for (int j = 0; j < 4; ++j) {
      Oa[j][0] *= al[0];
      Oa[j][1] *= al[1];
      Oa[j][2] *= al[2];
      Oa[j][3] *= al[3];
    }
    f16* Pw = Ps + wave * 1024;
#pragma unroll
    for (int jn = 0; jn < 4; ++jn)
#pragma unroll
      for (int r = 0; r < 4; ++r)
        Pw[((jn * 2 + (m16 >> 3)) * 16 + quad * 4 + r) * 8 + (m16 & 7)] =
            (f16)S[jn][r];
    const f16x8 pf0 = *(const f16x8*)&Pw[(quad * 16 + m16) * 8];
    const f16x8 pf1 = *(const f16x8*)&Pw[((4 + quad) * 16 + m16) * 8];
#pragma unroll
    for (int jd = 0; jd < 4; ++jd) {
      const f16x8 vf0 = *(const f16x8*)&Vs[cur][(jd * 16 + m16) * 64 + c0];
      const f16x8 vf1 = *(const f16x8*)&Vs[cur][(jd * 16 + m16) * 64 + c1];
      Oa[jd] = __builtin_amdgcn_mfma_f32_16x16x32_f16(pf0, vf0, Oa[jd], 0, 0, 0);
      Oa[jd] = __builtin_amdgcn_mfma_f32_16x16x32_f16(pf1, vf1, Oa[jd], 0, 0, 0);
    }
    // Trailing barrier: next iteration's stage overwrites buf[cur^1]'s
    // partner only after every wave finished reading this tile.
    __builtin_amdgcn_s_barrier();
  }
#pragma unroll
  for (int jd = 0; jd < 4; ++jd)
#pragma unroll
    for (int r = 0; r < 4; ++r) {
      const float v = Oa[jd][r] / l_run[r];
      const size_t off = (long long)b * sOb +
                         (size_t)(q0 + wave * 16 + quad * 4 + r) * D_ + h * 64 +
                         jd * 16 + m16;
      O[off] = (f16)v;
    }
}

// ---------------------------------------------------------------------------
extern "C" void kernel_launch(void* const* d_in, const int* in_sizes, int n_in,
                              void* d_out, int out_size, void* d_ws,
                              size_t ws_size, hipStream_t stream) {
  const float* x = (const float*)d_in[0];
  const float* coords = (const float*)d_in[1];
  const unsigned char* isctx = (const unsigned char*)d_in[2];
  const float* rope = (const float*)d_in[3];
  const float* ctx_in_w = (const float*)d_in[4];
  const float* ctx_in_b = (const float*)d_in[5];
  const float* ctx_out_w = (const float*)d_in[6];
  const float* ctx_out_b = (const float*)d_in[7];
  const float* tgt_in_w = (const float*)d_in[8];
  const float* tgt_in_b = (const float*)d_in[9];
  const float* tgt_out_w = (const float*)d_in[10];
  const float* tgt_out_b = (const float*)d_in[11];
  float* out = (float*)d_out;

  // ws layout (f16 units): tok 8M | wcat 8M | qkvc 12M | kvt 8M | qt 4M |
  // vt 4M | pos/ipos ints
  f16* ws = (f16*)d_ws;
  f16* tok = ws;
  f16* wcat = tok + 8388608;
  f16* qkvc = wcat + 8388608;
  f16* kvt = qkvc + 12582912;
  f16* qt = kvt + 8388608;
  f16* vt = qt + 4194304;
  int* pos = (int*)(vt + 4194304);
  int* ipos = pos + B_ * K_;

  partition_kernel<<<B_, 256, 0, stream>>>(isctx, pos, ipos);
  cvt_all<<<8192, 256, 0, stream>>>(ctx_in_w, tgt_in_w, ctx_out_w, tgt_out_w,
                                    wcat);
  rope_kernel<<<B_ * K_, 256, 0, stream>>>(x, coords, rope, ipos, tok);

  // Merged projection: ctx QKV + tgt KV + tgt Q in one dispatch.
  gemm_proj<<<dim3(48, 8, B_), 256, 0, stream>>>(tok, wcat, ctx_in_b,
                                                 tgt_in_b, qkvc, kvt, qt);

  // ctx self-attention (output overwrites tok rows 0..1023)
  vtrans_kernel<<<dim3(16, H_, B_), 256, 0, stream>>>(
      (const ushort_t*)qkvc, (long long)NCTX_ * 3 * D_, 3 * D_, 2 * D_,
      (ushort_t*)vt);
  attn_mfma<<<dim3(16, H_, B_), 256, 0, stream>>>(
      qkvc, (long long)NCTX_ * 3 * D_, 3 * D_, qkvc + D_,
      (long long)NCTX_ * 3 * D_, 3 * D_, vt, tok, (long long)K_ * D_);
  // tgt cross-attention
  vtrans_kernel<<<dim3(16, H_, B_), 256, 0, stream>>>(
      (const ushort_t*)kvt, (long long)NCTX_ * 2 * D_, 2 * D_, D_,
      (ushort_t*)vt);
  attn_mfma<<<dim3(16, H_, B_), 256, 0, stream>>>(
      qt, (long long)NCTX_ * D_, D_, kvt, (long long)NCTX_ * 2 * D_, 2 * D_,
      vt, tok + (size_t)NCTX_ * D_, (long long)K_ * D_);

  // Merged output projections (fp32, scattered to original order)
  gemm_out<<<dim3(8, 8, 2 * B_), 256, 0, stream>>>(
      tok, wcat + 6291456, ctx_out_b, tgt_out_b, ipos, out);
}

// Round 5
// 325.216 us; speedup vs baseline: 1.1053x; 1.1053x over previous
//
#include <hip/hip_runtime.h>
#include <math.h>

#define B_    4
#define K_    2048
#define D_    1024
#define H_    16
#define NCTX_ 1024

typedef unsigned short ushort_t;
typedef _Float16 f16;
typedef __attribute__((ext_vector_type(8))) _Float16 f16x8;
typedef __attribute__((ext_vector_type(4))) float f32x4;

union U4 {
  f16 h[4];
  ushort4 u;
};

union P4 {
  f16 h[4];
  ushort4 u;  // 8 bytes -> one ds_write_b64
};

__device__ __forceinline__ void gload16(const void* g, void* l) {
  __builtin_amdgcn_global_load_lds(
      (const __attribute__((address_space(1))) unsigned int*)g,
      (__attribute__((address_space(3))) unsigned int*)l, 16, 0, 0);
}

// ---------------------------------------------------------------------------
// Kernel 1: partition scan (verified R1-R4).
// ---------------------------------------------------------------------------
__global__ __launch_bounds__(256) void partition_kernel(
    const unsigned char* __restrict__ isctx, int* __restrict__ pos,
    int* __restrict__ ipos) {
  const int b = blockIdx.x;
  const int tid = threadIdx.x;
  const int wid = tid >> 6, lane = tid & 63;
  __shared__ int csum[4];
  __shared__ int waveTot[4];
  __shared__ int strideSh;

  int cnt = 0;
  for (int i = 0; i < 32; ++i) cnt += (isctx[tid * 32 + i] != 0);
  for (int off = 32; off; off >>= 1) cnt += __shfl_down(cnt, off, 64);
  if (lane == 0) csum[wid] = cnt;
  __syncthreads();
  if (tid == 0) {
    int t = csum[0] + csum[1] + csum[2] + csum[3];
    strideSh = (t > 2048) ? 1 : ((t > 768) ? 4 : 8);
  }
  __syncthreads();
  const int stride = strideSh;

  const unsigned char* base = isctx + (size_t)b * K_ * stride;
  int f[8];
  int s = 0;
  for (int i = 0; i < 8; ++i) {
    f[i] = base[(size_t)(tid * 8 + i) * stride] != 0;
    s += f[i];
  }
  int inc = s;
  for (int off = 1; off < 64; off <<= 1) {
    int v = __shfl_up(inc, off, 64);
    if (lane >= off) inc += v;
  }
  if (lane == 63) waveTot[wid] = inc;
  __syncthreads();
  int wOff = 0;
  for (int w = 0; w < wid; ++w) wOff += waveTot[w];
  int run = wOff + inc - s;
  for (int i = 0; i < 8; ++i) {
    int k = tid * 8 + i;
    int p;
    if (f[i]) {
      p = run;
      run++;
    } else {
      p = NCTX_ + k - run;
    }
    pos[b * K_ + k] = p;
    ipos[b * K_ + p] = k;
  }
}

// ---------------------------------------------------------------------------
// Kernel 2: RoPE + permute-gather -> f16 token buffer.
// ---------------------------------------------------------------------------
__global__ __launch_bounds__(256) void rope_kernel(
    const float* __restrict__ x, const float* __restrict__ coords,
    const float* __restrict__ cache, const int* __restrict__ ipos,
    f16* __restrict__ tok) {
  const int row = blockIdx.x;
  const int b = row >> 11;
  const int r = row & (K_ - 1);
  const int k = ipos[row];
  const int t = threadIdx.x;

  const float cy = coords[(size_t)(b * K_ + k) * 2 + 0];
  const float cx = coords[(size_t)(b * K_ + k) * 2 + 1];
  const int ypos = (int)fminf(fmaxf(cy / 224.0f * 1023.0f, 0.0f), 1023.0f);
  const int xpos = (int)fminf(fmaxf(cx / 224.0f * 1023.0f, 0.0f), 1023.0f);

  const float4 v = ((const float4*)(x + ((size_t)b * K_ + k) * D_))[t];
  const int e = 4 * t;
  const float* crow;
  int coff;
  if (e < 512) {
    crow = cache + (size_t)xpos * 512;
    coff = e;
  } else {
    crow = cache + (size_t)ypos * 512;
    coff = e - 512;
  }
  const float4 cs = *(const float4*)(crow + coff);
  float o[4];
  o[0] = v.x * cs.x - v.y * cs.y;
  o[1] = v.x * cs.y + v.y * cs.x;
  o[2] = v.z * cs.z - v.w * cs.w;
  o[3] = v.z * cs.w + v.w * cs.z;
  U4 h;
#pragma unroll
  for (int i = 0; i < 4; ++i) h.h[i] = (f16)o[i];
  ((ushort4*)(tok + ((size_t)b * K_ + r) * D_))[t] = h.u;
}

// ---------------------------------------------------------------------------
// Kernel 3: all weights fp32 -> f16, concatenated:
// [0,3M) ctx_in | [3M,5M) tgt_in kv | [5M,6M) tgt_in q | [6M,7M) ctx_out |
// [7M,8M) tgt_out   (M = 1048576 floats)
// ---------------------------------------------------------------------------
__global__ __launch_bounds__(256) void cvt_all(
    const float* __restrict__ ctx_in_w, const float* __restrict__ tgt_in_w,
    const float* __restrict__ ctx_out_w, const float* __restrict__ tgt_out_w,
    f16* __restrict__ dst) {
  const int i4 = blockIdx.x * 256 + threadIdx.x;  // 0..2097151
  const int f = i4 * 4;
  const float* src;
  if (f < 3145728) src = ctx_in_w + f;
  else if (f < 5242880) src = tgt_in_w + (f - 3145728 + 1048576);
  else if (f < 6291456) src = tgt_in_w + (f - 5242880);
  else if (f < 7340032) src = ctx_out_w + (f - 6291456);
  else src = tgt_out_w + (f - 7340032);
  const float4 v = *(const float4*)src;
  U4 u;
  u.h[0] = (f16)v.x;
  u.h[1] = (f16)v.y;
  u.h[2] = (f16)v.z;
  u.h[3] = (f16)v.w;
  ((ushort4*)dst)[i4] = u.u;
}

// ---------------------------------------------------------------------------
// GEMM core v3 (verified R3): coalesced staging (8-lane contiguous 128-B row
// segments), row-major [128][64] LDS with both-sides XOR swizzle, BK=64,
// double-buffered, counted vmcnt(8). gemm_proj 120 -> 75.8us, conflicts 0.
// ---------------------------------------------------------------------------
#define GEMM_PRE(AP, WP, Kd)                                                  \
  const int rb_ = wave * 8 + (lane >> 3);         /* row 0..31 (j adds 32) */ \
  const int kk_ = ((lane & 7) ^ (lane >> 3)) * 8; /* pre-swizzled k-chunk */  \
  const f16* gA_ = (AP) + (size_t)rb_ * (Kd) + kk_;                           \
  const f16* gW_ = (WP) + (size_t)rb_ * (Kd) + kk_;                           \
  const int lA_ = wave * 8 * 64 + lane * 8; /* == row*64 + kkchunk*8 */

#define GEMM_STAGE(k0s, bb)                                                   \
  _Pragma("unroll") for (int j = 0; j < 4; ++j) {                             \
    gload16(gA_ + (size_t)j * 32 * Kd_ + (k0s), &lds[(bb) + j * 2048 + lA_]); \
    gload16(gW_ + (size_t)j * 32 * Kd_ + (k0s),                               \
            &lds[(bb) + 8192 + j * 2048 + lA_]);                              \
  }

#define GEMM_TILE(bb)                                                         \
  _Pragma("unroll") for (int kh = 0; kh < 2; ++kh) {                          \
    f16x8 af[4], wf[4];                                                       \
    _Pragma("unroll") for (int i = 0; i < 4; ++i) {                           \
      const int ca = ((kh * 4 + quad) ^ (m16 & 7)) * 8;                       \
      af[i] = *(const f16x8*)&lds[(bb) + (wm + i * 16 + m16) * 64 + ca];      \
      wf[i] =                                                                 \
          *(const f16x8*)&lds[(bb) + 8192 + (wn + i * 16 + m16) * 64 + ca];   \
    }                                                                         \
    _Pragma("unroll") for (int i = 0; i < 4; ++i)                             \
        _Pragma("unroll") for (int j = 0; j < 4; ++j)                         \
      acc[i][j] = __builtin_amdgcn_mfma_f32_16x16x32_f16(af[i], wf[j],        \
                                                         acc[i][j], 0, 0, 0); \
  }

#define GEMM_CORE(AP, WP, Kd)                                                 \
  f32x4 acc[4][4];                                                            \
  {                                                                           \
    const f32x4 z = {0.f, 0.f, 0.f, 0.f};                                     \
    for (int i = 0; i < 4; ++i)                                               \
      for (int j = 0; j < 4; ++j) acc[i][j] = z;                              \
  }                                                                           \
  const int Kd_ = (Kd);                                                       \
  GEMM_PRE(AP, WP, Kd_)                                                       \
  GEMM_STAGE(0, 0)                                                            \
  for (int t = 0; t < Kd_ / 64; ++t) {                                        \
    const int cb = (t & 1) * 16384;                                           \
    if (t + 1 < Kd_ / 64) {                                                   \
      GEMM_STAGE((t + 1) * 64, ((t + 1) & 1) * 16384)                         \
      asm volatile("s_waitcnt vmcnt(8)" ::: "memory");                        \
    } else {                                                                  \
      asm volatile("s_waitcnt vmcnt(0)" ::: "memory");                        \
    }                                                                         \
    __builtin_amdgcn_s_barrier();                                             \
    asm volatile("" ::: "memory");                                            \
    GEMM_TILE(cb)                                                             \
    asm volatile("" ::: "memory");                                            \
    __builtin_amdgcn_s_barrier();                                             \
  }

// ---------------------------------------------------------------------------
// Kernel 4: merged projection GEMM. grid (48, 8, 4):
//   nb < 40: ctx rows x [ctx_in QKV (3072) | tgt_in KV (2048)] -> qkvc / kvt
//   nb >= 40: tgt rows x tgt_in Q (1024) -> qt
// ---------------------------------------------------------------------------
__global__ __launch_bounds__(256, 2) void gemm_proj(
    const f16* __restrict__ tok, const f16* __restrict__ wcat,
    const float* __restrict__ ctx_in_b, const float* __restrict__ tgt_in_b,
    f16* __restrict__ qkvc, f16* __restrict__ kvt, f16* __restrict__ qt) {
  __shared__ f16 lds[32768];
  const int tid = threadIdx.x;
  const int wave = tid >> 6, lane = tid & 63;
  const int quad = lane >> 4, m16 = lane & 15;
  const int nb = blockIdx.x, mb = blockIdx.y, b = blockIdx.z;
  const int wm = (wave & 1) << 6, wn = (wave >> 1) << 6;
  const int m0 = mb * 128;
  const bool isQ = nb >= 40;
  const int n0 = isQ ? (nb - 40) * 128 : nb * 128;
  const f16* AP = tok + (size_t)b * K_ * D_ +
                  (isQ ? (size_t)NCTX_ * D_ : (size_t)0) + (size_t)m0 * D_;
  const f16* WP = wcat + (isQ ? (size_t)5242880 : (size_t)0) +
                  (size_t)n0 * D_;

  GEMM_CORE(AP, WP, D_)

#pragma unroll
  for (int j = 0; j < 4; ++j) {
    const int col = n0 + wn + j * 16 + m16;
    float bv;
    f16* dst;
    int ldc, dcol;
    if (isQ) {
      bv = tgt_in_b[col];
      dst = qt + (size_t)b * NCTX_ * D_;
      ldc = D_;
      dcol = col;
    } else if (col < 3072) {
      bv = ctx_in_b[col];
      dst = qkvc + (size_t)b * NCTX_ * 3072;
      ldc = 3072;
      dcol = col;
    } else {
      bv = tgt_in_b[D_ + col - 3072];
      dst = kvt + (size_t)b * NCTX_ * 2048;
      ldc = 2048;
      dcol = col - 3072;
    }
#pragma unroll
    for (int i = 0; i < 4; ++i) {
      const int mr = m0 + wm + i * 16 + quad * 4;
#pragma unroll
      for (int r = 0; r < 4; ++r)
        dst[(size_t)(mr + r) * ldc + dcol] = (f16)(acc[i][j][r] + bv);
    }
  }
}

// ---------------------------------------------------------------------------
// Kernel 5: merged output projections. grid (8, 8, 8): b = z&3, sel = z>>2.
// fp32 output scattered to original token order (16-lane 64B segments ->
// already fully coalesced).
// ---------------------------------------------------------------------------
__global__ __launch_bounds__(256, 2) void gemm_out(
    const f16* __restrict__ Atok, const f16* __restrict__ Wbase,
    const float* __restrict__ bias_ctx, const float* __restrict__ bias_tgt,
    const int* __restrict__ ipos, float* __restrict__ out) {
  __shared__ f16 lds[32768];
  const int tid = threadIdx.x;
  const int wave = tid >> 6, lane = tid & 63;
  const int quad = lane >> 4, m16 = lane & 15;
  const int n0 = blockIdx.x * 128, m0 = blockIdx.y * 128;
  const int b = blockIdx.z & 3, sel = blockIdx.z >> 2;
  const int wm = (wave & 1) << 6, wn = (wave >> 1) << 6;
  const f16* AP = Atok + (size_t)b * K_ * D_ + (size_t)sel * NCTX_ * D_ +
                  (size_t)m0 * D_;
  const f16* WP = Wbase + (size_t)sel * 1048576 + (size_t)n0 * D_;
  const float* bias = sel ? bias_tgt : bias_ctx;

  GEMM_CORE(AP, WP, D_)

#pragma unroll
  for (int j = 0; j < 4; ++j) {
    const int col = n0 + wn + j * 16 + m16;
    const float bv = bias[col];
#pragma unroll
    for (int i = 0; i < 4; ++i) {
      const int mr = m0 + wm + i * 16 + quad * 4;
#pragma unroll
      for (int r = 0; r < 4; ++r) {
        const int orow = ipos[b * K_ + sel * NCTX_ + mr + r];
        out[(size_t)b * K_ * D_ + (size_t)orow * D_ + col] =
            acc[i][j][r] + bv;
      }
    }
  }
}

// ---------------------------------------------------------------------------
// Kernel 6: V transpose (16-bit moves).
// ---------------------------------------------------------------------------
__global__ __launch_bounds__(256) void vtrans_kernel(
    const ushort_t* __restrict__ V, long long sVb, int ldv, int coloff,
    ushort_t* __restrict__ Vt) {
  __shared__ __align__(16) ushort_t tile[64][72];
  const int tblk = blockIdx.x, h = blockIdx.y, b = blockIdx.z;
  const int tid = threadIdx.x;
  const ushort_t* src =
      V + (long long)b * sVb + (size_t)(tblk * 64) * ldv + coloff + h * 64;
#pragma unroll
  for (int j = 0; j < 2; ++j) {
    const int c = j * 256 + tid;
    const int r = c >> 3, dc = c & 7;
    *(uint4*)&tile[r][dc * 8] = *(const uint4*)(src + (size_t)r * ldv + dc * 8);
  }
  __syncthreads();
  ushort_t* dst = Vt + (size_t)(b * H_ + h) * 64 * 1024 + tblk * 64;
#pragma unroll
  for (int j = 0; j < 2; ++j) {
    const int c = j * 256 + tid;
    const int d = c >> 3, tc = c & 7;
    union {
      ushort_t u[8];
      uint4 v;
    } t;
#pragma unroll
    for (int i = 0; i < 8; ++i) t.u[i] = tile[tc * 8 + i][d];
    *(uint4*)(dst + (size_t)d * 1024 + tc * 8) = t.v;
  }
}

// ---------------------------------------------------------------------------
// Kernel 7: MFMA flash attention v3 — swapped QK^T (S^T = mfma(K,Q), same
// LDS reads, args swapped) makes the q-row lane-local (q = m16):
//   - kv-reduction: 15 in-lane fmax/fadd + 2 shfl_xor (was 16 vals x 4-deep
//     shuffle chains = 32 shuffles/kt through the DS pipe)
//   - m/l are per-lane scalars
//   - P store: 4x ds_write_b64 XOR-swizzled (was 16 scalar b16, 2.1M confl)
//   - P overlays Qs after the Q-fragment hoist (wave-private region = own Q
//     rows; in-wave DS ordering + data dep make it safe) -> LDS 40 KB ->
//     4 blocks/CU (R4's 48 KB cost a residency slot).
//   - al broadcast into the q=quad*4+r output domain: 4 bpermutes/kt.
// Staging (coalesced + swizzled + dbuf + counted vmcnt) unchanged from R4.
// ---------------------------------------------------------------------------
__global__ __launch_bounds__(256) void attn_mfma(
    const f16* __restrict__ Qp, long long sQb, int ldq,
    const f16* __restrict__ Kp, long long sKb, int ldk,
    const f16* __restrict__ Vt, f16* __restrict__ O, long long sOb) {
  __shared__ f16 QP[4096];  // Q staging; reused as P after fragment hoist
  __shared__ f16 Ks[2][4096];
  __shared__ f16 Vs[2][4096];
  const int tid = threadIdx.x, wave = tid >> 6, lane = tid & 63;
  const int quad = lane >> 4, m16 = lane & 15;
  const int q0 = blockIdx.x * 64, h = blockIdx.y, b = blockIdx.z;
  const f16* Qb = Qp + (long long)b * sQb + h * 64;
  const f16* Kb = Kp + (long long)b * sKb + h * 64;
  const f16* Vb = Vt + (size_t)(b * H_ + h) * 64 * 1024;

  // Coalesced staging geometry: 8 lanes per row, contiguous 128-B segment.
  const int rL = lane >> 3;               // row & 7
  const int kkc = ((lane & 7) ^ rL) * 8;  // pre-swizzled source chunk
  const int lB = wave * 512 + lane * 8;   // linear LDS dest (f16)

#pragma unroll
  for (int j = 0; j < 2; ++j) {
    const int row = j * 32 + wave * 8 + rL;
    gload16(Qb + (size_t)(q0 + row) * ldq + kkc, &QP[j * 2048 + lB]);
  }
#pragma unroll
  for (int j = 0; j < 2; ++j) {
    const int row = j * 32 + wave * 8 + rL;
    gload16(Kb + (size_t)row * ldk + kkc, &Ks[0][j * 2048 + lB]);
    gload16(Vb + (size_t)row * 1024 + kkc, &Vs[0][j * 2048 + lB]);
  }

  float m_run = -1e30f, l_run = 0.f;
  f32x4 Oa[4];
  const f32x4 z = {0.f, 0.f, 0.f, 0.f};
#pragma unroll
  for (int j = 0; j < 4; ++j) Oa[j] = z;

  // Wait own Q loads (oldest 2 of 6 outstanding), barrier -> all Q in.
  asm volatile("s_waitcnt vmcnt(4)" ::: "memory");
  __builtin_amdgcn_s_barrier();

  // Hoisted Q fragments (B-operand: n = q = m16).
  const int c0 = (quad ^ (m16 & 7)) * 8;
  const int c1 = ((quad + 4) ^ (m16 & 7)) * 8;
  const f16x8 qf0 = *(const f16x8*)&QP[(wave * 16 + m16) * 64 + c0];
  const f16x8 qf1 = *(const f16x8*)&QP[(wave * 16 + m16) * 64 + c1];

  // Wave-private P tile (16 q x 64 kv) overlays this wave's own Q rows.
  f16* Pw = QP + wave * 1024;

  for (int kt = 0; kt < 16; ++kt) {
    const int cur = kt & 1;
    if (kt < 15) {
#pragma unroll
      for (int j = 0; j < 2; ++j) {
        const int row = j * 32 + wave * 8 + rL;
        gload16(Kb + (size_t)((kt + 1) * 64 + row) * ldk + kkc,
                &Ks[cur ^ 1][j * 2048 + lB]);
        gload16(Vb + (size_t)row * 1024 + (kt + 1) * 64 + kkc,
                &Vs[cur ^ 1][j * 2048 + lB]);
      }
      asm volatile("s_waitcnt vmcnt(4)" ::: "memory");  // tile kt landed
    } else {
      asm volatile("s_waitcnt vmcnt(0)" ::: "memory");
    }
    __builtin_amdgcn_s_barrier();

    // Swapped QK^T: lane holds S^T[kv = jn*16 + quad*4 + r][q = m16].
    f32x4 S[4];
    __builtin_amdgcn_s_setprio(1);
#pragma unroll
    for (int jn = 0; jn < 4; ++jn) {
      S[jn] = z;
      const f16x8 kf0 = *(const f16x8*)&Ks[cur][(jn * 16 + m16) * 64 + c0];
      const f16x8 kf1 = *(const f16x8*)&Ks[cur][(jn * 16 + m16) * 64 + c1];
      S[jn] = __builtin_amdgcn_mfma_f32_16x16x32_f16(kf0, qf0, S[jn], 0, 0, 0);
      S[jn] = __builtin_amdgcn_mfma_f32_16x16x32_f16(kf1, qf1, S[jn], 0, 0, 0);
    }
    __builtin_amdgcn_s_setprio(0);

    // Row max: 15 in-lane fmax (tree) + butterfly over quad groups.
    float mv0 = fmaxf(fmaxf(S[0][0], S[1][0]), fmaxf(S[2][0], S[3][0]));
    float mv1 = fmaxf(fmaxf(S[0][1], S[1][1]), fmaxf(S[2][1], S[3][1]));
    float mv2 = fmaxf(fmaxf(S[0][2], S[1][2]), fmaxf(S[2][2], S[3][2]));
    float mv3 = fmaxf(fmaxf(S[0][3], S[1][3]), fmaxf(S[2][3], S[3][3]));
    float mx = fmaxf(fmaxf(mv0, mv1), fmaxf(mv2, mv3));
    mx = fmaxf(mx, __shfl_xor(mx, 16, 64));
    mx = fmaxf(mx, __shfl_xor(mx, 32, 64));
    mx *= 0.125f;
    const float mnew = fmaxf(m_run, mx);
    const float al = __expf(m_run - mnew);
    m_run = mnew;

    // P = exp(S*0.125 - mnew); pack 4 f16 -> one b64 per jn (swizzled).
    float rs = 0.f;
#pragma unroll
    for (int jn = 0; jn < 4; ++jn) {
      P4 p4;
#pragma unroll
      for (int r = 0; r < 4; ++r) {
        const float p = __expf(__builtin_fmaf(S[jn][r], 0.125f, -mnew));
        rs += p;
        p4.h[r] = (f16)p;
      }
      *(ushort4*)&Pw[m16 * 64 + (((jn * 2 + (quad >> 1)) ^ (m16 & 7)) * 8) +
                     (quad & 1) * 4] = p4.u;
    }
    rs += __shfl_xor(rs, 16, 64);
    rs += __shfl_xor(rs, 32, 64);
    l_run = l_run * al + rs;

    // Broadcast al into the PV output domain q = quad*4 + r.
    float alq[4];
#pragma unroll
    for (int r = 0; r < 4; ++r) alq[r] = __shfl(al, quad * 4 + r, 64);
#pragma unroll
    for (int j = 0; j < 4; ++j) {
      Oa[j][0] *= alq[0];
      Oa[j][1] *= alq[1];
      Oa[j][2] *= alq[2];
      Oa[j][3] *= alq[3];
    }

    // PV: A = P[q=m16][kv chunk quad] (swizzled read), B = V^T.
    const f16x8 pf0 = *(const f16x8*)&Pw[m16 * 64 + c0];
    const f16x8 pf1 = *(const f16x8*)&Pw[m16 * 64 + c1];
    __builtin_amdgcn_s_setprio(1);
#pragma unroll
    for (int jd = 0; jd < 4; ++jd) {
      const f16x8 vf0 = *(const f16x8*)&Vs[cur][(jd * 16 + m16) * 64 + c0];
      const f16x8 vf1 = *(const f16x8*)&Vs[cur][(jd * 16 + m16) * 64 + c1];
      Oa[jd] = __builtin_amdgcn_mfma_f32_16x16x32_f16(pf0, vf0, Oa[jd], 0, 0, 0);
      Oa[jd] = __builtin_amdgcn_mfma_f32_16x16x32_f16(pf1, vf1, Oa[jd], 0, 0, 0);
    }
    __builtin_amdgcn_s_setprio(0);
    __builtin_amdgcn_s_barrier();
  }

  // l broadcast into output domain, then scale + store.
  float lq[4];
#pragma unroll
  for (int r = 0; r < 4; ++r) lq[r] = 1.0f / __shfl(l_run, quad * 4 + r, 64);
#pragma unroll
  for (int jd = 0; jd < 4; ++jd)
#pragma unroll
    for (int r = 0; r < 4; ++r) {
      const float v = Oa[jd][r] * lq[r];
      const size_t off = (long long)b * sOb +
                         (size_t)(q0 + wave * 16 + quad * 4 + r) * D_ + h * 64 +
                         jd * 16 + m16;
      O[off] = (f16)v;
    }
}

// ---------------------------------------------------------------------------
extern "C" void kernel_launch(void* const* d_in, const int* in_sizes, int n_in,
                              void* d_out, int out_size, void* d_ws,
                              size_t ws_size, hipStream_t stream) {
  const float* x = (const float*)d_in[0];
  const float* coords = (const float*)d_in[1];
  const unsigned char* isctx = (const unsigned char*)d_in[2];
  const float* rope = (const float*)d_in[3];
  const float* ctx_in_w = (const float*)d_in[4];
  const float* ctx_in_b = (const float*)d_in[5];
  const float* ctx_out_w = (const float*)d_in[6];
  const float* ctx_out_b = (const float*)d_in[7];
  const float* tgt_in_w = (const float*)d_in[8];
  const float* tgt_in_b = (const float*)d_in[9];
  const float* tgt_out_w = (const float*)d_in[10];
  const float* tgt_out_b = (const float*)d_in[11];
  float* out = (float*)d_out;

  // ws layout (f16 units): tok 8M | wcat 8M | qkvc 12M | kvt 8M | qt 4M |
  // vt 4M | pos/ipos ints
  f16* ws = (f16*)d_ws;
  f16* tok = ws;
  f16* wcat = tok + 8388608;
  f16* qkvc = wcat + 8388608;
  f16* kvt = qkvc + 12582912;
  f16* qt = kvt + 8388608;
  f16* vt = qt + 4194304;
  int* pos = (int*)(vt + 4194304);
  int* ipos = pos + B_ * K_;

  partition_kernel<<<B_, 256, 0, stream>>>(isctx, pos, ipos);
  cvt_all<<<8192, 256, 0, stream>>>(ctx_in_w, tgt_in_w, ctx_out_w, tgt_out_w,
                                    wcat);
  rope_kernel<<<B_ * K_, 256, 0, stream>>>(x, coords, rope, ipos, tok);

  // Merged projection: ctx QKV + tgt KV + tgt Q in one dispatch.
  gemm_proj<<<dim3(48, 8, B_), 256, 0, stream>>>(tok, wcat, ctx_in_b,
                                                 tgt_in_b, qkvc, kvt, qt);

  // ctx self-attention (output overwrites tok rows 0..1023)
  vtrans_kernel<<<dim3(16, H_, B_), 256, 0, stream>>>(
      (const ushort_t*)qkvc, (long long)NCTX_ * 3 * D_, 3 * D_, 2 * D_,
      (ushort_t*)vt);
  attn_mfma<<<dim3(16, H_, B_), 256, 0, stream>>>(
      qkvc, (long long)NCTX_ * 3 * D_, 3 * D_, qkvc + D_,
      (long long)NCTX_ * 3 * D_, 3 * D_, vt, tok, (long long)K_ * D_);
  // tgt cross-attention
  vtrans_kernel<<<dim3(16, H_, B_), 256, 0, stream>>>(
      (const ushort_t*)kvt, (long long)NCTX_ * 2 * D_, 2 * D_, D_,
      (ushort_t*)vt);
  attn_mfma<<<dim3(16, H_, B_), 256, 0, stream>>>(
      qt, (long long)NCTX_ * D_, D_, kvt, (long long)NCTX_ * 2 * D_, 2 * D_,
      vt, tok + (size_t)NCTX_ * D_, (long long)K_ * D_);

  // Merged output projections (fp32, scattered to original order)
  gemm_out<<<dim3(8, 8, 2 * B_), 256, 0, stream>>>(
      tok, wcat + 6291456, ctx_out_b, tgt_out_b, ipos, out);
}

// Round 6
// 303.868 us; speedup vs baseline: 1.1830x; 1.0703x over previous
//
#include <hip/hip_runtime.h>
#include <math.h>

#define B_    4
#define K_    2048
#define D_    1024
#define H_    16
#define NCTX_ 1024

typedef unsigned short ushort_t;
typedef _Float16 f16;
typedef __attribute__((ext_vector_type(8))) _Float16 f16x8;
typedef __attribute__((ext_vector_type(4))) float f32x4;

union U4 {
  f16 h[4];
  ushort4 u;
};

union P4 {
  f16 h[4];
  ushort4 u;  // 8 bytes -> one ds_write_b64
};

__device__ __forceinline__ void gload16(const void* g, void* l) {
  __builtin_amdgcn_global_load_lds(
      (const __attribute__((address_space(1))) unsigned int*)g,
      (__attribute__((address_space(3))) unsigned int*)l, 16, 0, 0);
}

// ---------------------------------------------------------------------------
// Kernel 1: partition scan (verified R1-R4).
// ---------------------------------------------------------------------------
__global__ __launch_bounds__(256) void partition_kernel(
    const unsigned char* __restrict__ isctx, int* __restrict__ pos,
    int* __restrict__ ipos) {
  const int b = blockIdx.x;
  const int tid = threadIdx.x;
  const int wid = tid >> 6, lane = tid & 63;
  __shared__ int csum[4];
  __shared__ int waveTot[4];
  __shared__ int strideSh;

  int cnt = 0;
  for (int i = 0; i < 32; ++i) cnt += (isctx[tid * 32 + i] != 0);
  for (int off = 32; off; off >>= 1) cnt += __shfl_down(cnt, off, 64);
  if (lane == 0) csum[wid] = cnt;
  __syncthreads();
  if (tid == 0) {
    int t = csum[0] + csum[1] + csum[2] + csum[3];
    strideSh = (t > 2048) ? 1 : ((t > 768) ? 4 : 8);
  }
  __syncthreads();
  const int stride = strideSh;

  const unsigned char* base = isctx + (size_t)b * K_ * stride;
  int f[8];
  int s = 0;
  for (int i = 0; i < 8; ++i) {
    f[i] = base[(size_t)(tid * 8 + i) * stride] != 0;
    s += f[i];
  }
  int inc = s;
  for (int off = 1; off < 64; off <<= 1) {
    int v = __shfl_up(inc, off, 64);
    if (lane >= off) inc += v;
  }
  if (lane == 63) waveTot[wid] = inc;
  __syncthreads();
  int wOff = 0;
  for (int w = 0; w < wid; ++w) wOff += waveTot[w];
  int run = wOff + inc - s;
  for (int i = 0; i < 8; ++i) {
    int k = tid * 8 + i;
    int p;
    if (f[i]) {
      p = run;
      run++;
    } else {
      p = NCTX_ + k - run;
    }
    pos[b * K_ + k] = p;
    ipos[b * K_ + p] = k;
  }
}

// ---------------------------------------------------------------------------
// Kernel 2: RoPE + permute-gather -> f16 token buffer.
// ---------------------------------------------------------------------------
__global__ __launch_bounds__(256) void rope_kernel(
    const float* __restrict__ x, const float* __restrict__ coords,
    const float* __restrict__ cache, const int* __restrict__ ipos,
    f16* __restrict__ tok) {
  const int row = blockIdx.x;
  const int b = row >> 11;
  const int r = row & (K_ - 1);
  const int k = ipos[row];
  const int t = threadIdx.x;

  const float cy = coords[(size_t)(b * K_ + k) * 2 + 0];
  const float cx = coords[(size_t)(b * K_ + k) * 2 + 1];
  const int ypos = (int)fminf(fmaxf(cy / 224.0f * 1023.0f, 0.0f), 1023.0f);
  const int xpos = (int)fminf(fmaxf(cx / 224.0f * 1023.0f, 0.0f), 1023.0f);

  const float4 v = ((const float4*)(x + ((size_t)b * K_ + k) * D_))[t];
  const int e = 4 * t;
  const float* crow;
  int coff;
  if (e < 512) {
    crow = cache + (size_t)xpos * 512;
    coff = e;
  } else {
    crow = cache + (size_t)ypos * 512;
    coff = e - 512;
  }
  const float4 cs = *(const float4*)(crow + coff);
  float o[4];
  o[0] = v.x * cs.x - v.y * cs.y;
  o[1] = v.x * cs.y + v.y * cs.x;
  o[2] = v.z * cs.z - v.w * cs.w;
  o[3] = v.z * cs.w + v.w * cs.z;
  U4 h;
#pragma unroll
  for (int i = 0; i < 4; ++i) h.h[i] = (f16)o[i];
  ((ushort4*)(tok + ((size_t)b * K_ + r) * D_))[t] = h.u;
}

// ---------------------------------------------------------------------------
// Kernel 3: all weights fp32 -> f16, concatenated:
// [0,3M) ctx_in | [3M,5M) tgt_in kv | [5M,6M) tgt_in q | [6M,7M) ctx_out |
// [7M,8M) tgt_out   (M = 1048576 floats)
// ---------------------------------------------------------------------------
__global__ __launch_bounds__(256) void cvt_all(
    const float* __restrict__ ctx_in_w, const float* __restrict__ tgt_in_w,
    const float* __restrict__ ctx_out_w, const float* __restrict__ tgt_out_w,
    f16* __restrict__ dst) {
  const int i4 = blockIdx.x * 256 + threadIdx.x;  // 0..2097151
  const int f = i4 * 4;
  const float* src;
  if (f < 3145728) src = ctx_in_w + f;
  else if (f < 5242880) src = tgt_in_w + (f - 3145728 + 1048576);
  else if (f < 6291456) src = tgt_in_w + (f - 5242880);
  else if (f < 7340032) src = ctx_out_w + (f - 6291456);
  else src = tgt_out_w + (f - 7340032);
  const float4 v = *(const float4*)src;
  U4 u;
  u.h[0] = (f16)v.x;
  u.h[1] = (f16)v.y;
  u.h[2] = (f16)v.z;
  u.h[3] = (f16)v.w;
  ((ushort4*)dst)[i4] = u.u;
}

// ---------------------------------------------------------------------------
// GEMM core v3 (verified R3): coalesced staging (8-lane contiguous 128-B row
// segments), row-major [128][64] LDS with both-sides XOR swizzle, BK=64,
// double-buffered, counted vmcnt(8). gemm_proj 120 -> 75.8us, conflicts 0.
// ---------------------------------------------------------------------------
#define GEMM_PRE(AP, WP, Kd)                                                  \
  const int rb_ = wave * 8 + (lane >> 3);         /* row 0..31 (j adds 32) */ \
  const int kk_ = ((lane & 7) ^ (lane >> 3)) * 8; /* pre-swizzled k-chunk */  \
  const f16* gA_ = (AP) + (size_t)rb_ * (Kd) + kk_;                           \
  const f16* gW_ = (WP) + (size_t)rb_ * (Kd) + kk_;                           \
  const int lA_ = wave * 8 * 64 + lane * 8; /* == row*64 + kkchunk*8 */

#define GEMM_STAGE(k0s, bb)                                                   \
  _Pragma("unroll") for (int j = 0; j < 4; ++j) {                             \
    gload16(gA_ + (size_t)j * 32 * Kd_ + (k0s), &lds[(bb) + j * 2048 + lA_]); \
    gload16(gW_ + (size_t)j * 32 * Kd_ + (k0s),                               \
            &lds[(bb) + 8192 + j * 2048 + lA_]);                              \
  }

#define GEMM_TILE(bb)                                                         \
  _Pragma("unroll") for (int kh = 0; kh < 2; ++kh) {                          \
    f16x8 af[4], wf[4];                                                       \
    _Pragma("unroll") for (int i = 0; i < 4; ++i) {                           \
      const int ca = ((kh * 4 + quad) ^ (m16 & 7)) * 8;                       \
      af[i] = *(const f16x8*)&lds[(bb) + (wm + i * 16 + m16) * 64 + ca];      \
      wf[i] =                                                                 \
          *(const f16x8*)&lds[(bb) + 8192 + (wn + i * 16 + m16) * 64 + ca];   \
    }                                                                         \
    _Pragma("unroll") for (int i = 0; i < 4; ++i)                             \
        _Pragma("unroll") for (int j = 0; j < 4; ++j)                         \
      acc[i][j] = __builtin_amdgcn_mfma_f32_16x16x32_f16(af[i], wf[j],        \
                                                         acc[i][j], 0, 0, 0); \
  }

#define GEMM_CORE(AP, WP, Kd)                                                 \
  f32x4 acc[4][4];                                                            \
  {                                                                           \
    const f32x4 z = {0.f, 0.f, 0.f, 0.f};                                     \
    for (int i = 0; i < 4; ++i)                                               \
      for (int j = 0; j < 4; ++j) acc[i][j] = z;                              \
  }                                                                           \
  const int Kd_ = (Kd);                                                       \
  GEMM_PRE(AP, WP, Kd_)                                                       \
  GEMM_STAGE(0, 0)                                                            \
  for (int t = 0; t < Kd_ / 64; ++t) {                                        \
    const int cb = (t & 1) * 16384;                                           \
    if (t + 1 < Kd_ / 64) {                                                   \
      GEMM_STAGE((t + 1) * 64, ((t + 1) & 1) * 16384)                         \
      asm volatile("s_waitcnt vmcnt(8)" ::: "memory");                        \
    } else {                                                                  \
      asm volatile("s_waitcnt vmcnt(0)" ::: "memory");                        \
    }                                                                         \
    __builtin_amdgcn_s_barrier();                                             \
    asm volatile("" ::: "memory");                                            \
    GEMM_TILE(cb)                                                             \
    asm volatile("" ::: "memory");                                            \
    __builtin_amdgcn_s_barrier();                                             \
  }

// ---------------------------------------------------------------------------
// Kernel 4: merged projection GEMM. grid (48, 8, 4):
//   nb < 40: ctx rows x [ctx_in QKV (3072) | tgt_in KV (2048)] -> qkvc / kvt
//   nb >= 40: tgt rows x tgt_in Q (1024) -> qt
// ---------------------------------------------------------------------------
__global__ __launch_bounds__(256, 2) void gemm_proj(
    const f16* __restrict__ tok, const f16* __restrict__ wcat,
    const float* __restrict__ ctx_in_b, const float* __restrict__ tgt_in_b,
    f16* __restrict__ qkvc, f16* __restrict__ kvt, f16* __restrict__ qt) {
  __shared__ f16 lds[32768];
  const int tid = threadIdx.x;
  const int wave = tid >> 6, lane = tid & 63;
  const int quad = lane >> 4, m16 = lane & 15;
  const int nb = blockIdx.x, mb = blockIdx.y, b = blockIdx.z;
  const int wm = (wave & 1) << 6, wn = (wave >> 1) << 6;
  const int m0 = mb * 128;
  const bool isQ = nb >= 40;
  const int n0 = isQ ? (nb - 40) * 128 : nb * 128;
  const f16* AP = tok + (size_t)b * K_ * D_ +
                  (isQ ? (size_t)NCTX_ * D_ : (size_t)0) + (size_t)m0 * D_;
  const f16* WP = wcat + (isQ ? (size_t)5242880 : (size_t)0) +
                  (size_t)n0 * D_;

  GEMM_CORE(AP, WP, D_)

#pragma unroll
  for (int j = 0; j < 4; ++j) {
    const int col = n0 + wn + j * 16 + m16;
    float bv;
    f16* dst;
    int ldc, dcol;
    if (isQ) {
      bv = tgt_in_b[col];
      dst = qt + (size_t)b * NCTX_ * D_;
      ldc = D_;
      dcol = col;
    } else if (col < 3072) {
      bv = ctx_in_b[col];
      dst = qkvc + (size_t)b * NCTX_ * 3072;
      ldc = 3072;
      dcol = col;
    } else {
      bv = tgt_in_b[D_ + col - 3072];
      dst = kvt + (size_t)b * NCTX_ * 2048;
      ldc = 2048;
      dcol = col - 3072;
    }
#pragma unroll
    for (int i = 0; i < 4; ++i) {
      const int mr = m0 + wm + i * 16 + quad * 4;
#pragma unroll
      for (int r = 0; r < 4; ++r)
        dst[(size_t)(mr + r) * ldc + dcol] = (f16)(acc[i][j][r] + bv);
    }
  }
}

// ---------------------------------------------------------------------------
// Kernel 5: merged output projections. grid (8, 8, 8): b = z&3, sel = z>>2.
// fp32 output scattered to original token order (16-lane 64B segments ->
// already fully coalesced).
// ---------------------------------------------------------------------------
__global__ __launch_bounds__(256, 2) void gemm_out(
    const f16* __restrict__ Atok, const f16* __restrict__ Wbase,
    const float* __restrict__ bias_ctx, const float* __restrict__ bias_tgt,
    const int* __restrict__ ipos, float* __restrict__ out) {
  __shared__ f16 lds[32768];
  const int tid = threadIdx.x;
  const int wave = tid >> 6, lane = tid & 63;
  const int quad = lane >> 4, m16 = lane & 15;
  const int n0 = blockIdx.x * 128, m0 = blockIdx.y * 128;
  const int b = blockIdx.z & 3, sel = blockIdx.z >> 2;
  const int wm = (wave & 1) << 6, wn = (wave >> 1) << 6;
  const f16* AP = Atok + (size_t)b * K_ * D_ + (size_t)sel * NCTX_ * D_ +
                  (size_t)m0 * D_;
  const f16* WP = Wbase + (size_t)sel * 1048576 + (size_t)n0 * D_;
  const float* bias = sel ? bias_tgt : bias_ctx;

  GEMM_CORE(AP, WP, D_)

#pragma unroll
  for (int j = 0; j < 4; ++j) {
    const int col = n0 + wn + j * 16 + m16;
    const float bv = bias[col];
#pragma unroll
    for (int i = 0; i < 4; ++i) {
      const int mr = m0 + wm + i * 16 + quad * 4;
#pragma unroll
      for (int r = 0; r < 4; ++r) {
        const int orow = ipos[b * K_ + sel * NCTX_ + mr + r];
        out[(size_t)b * K_ * D_ + (size_t)orow * D_ + col] =
            acc[i][j][r] + bv;
      }
    }
  }
}

// ---------------------------------------------------------------------------
// Kernel 6: V transpose (16-bit moves).
// ---------------------------------------------------------------------------
__global__ __launch_bounds__(256) void vtrans_kernel(
    const ushort_t* __restrict__ V, long long sVb, int ldv, int coloff,
    ushort_t* __restrict__ Vt) {
  __shared__ __align__(16) ushort_t tile[64][72];
  const int tblk = blockIdx.x, h = blockIdx.y, b = blockIdx.z;
  const int tid = threadIdx.x;
  const ushort_t* src =
      V + (long long)b * sVb + (size_t)(tblk * 64) * ldv + coloff + h * 64;
#pragma unroll
  for (int j = 0; j < 2; ++j) {
    const int c = j * 256 + tid;
    const int r = c >> 3, dc = c & 7;
    *(uint4*)&tile[r][dc * 8] = *(const uint4*)(src + (size_t)r * ldv + dc * 8);
  }
  __syncthreads();
  ushort_t* dst = Vt + (size_t)(b * H_ + h) * 64 * 1024 + tblk * 64;
#pragma unroll
  for (int j = 0; j < 2; ++j) {
    const int c = j * 256 + tid;
    const int d = c >> 3, tc = c & 7;
    union {
      ushort_t u[8];
      uint4 v;
    } t;
#pragma unroll
    for (int i = 0; i < 8; ++i) t.u[i] = tile[tc * 8 + i][d];
    *(uint4*)(dst + (size_t)d * 1024 + tc * 8) = t.v;
  }
}

// ---------------------------------------------------------------------------
// Kernel 7: MFMA flash attention v4 — QBLK 64->128, 8 waves (512 thr).
// Per-wave inner code identical to verified R5 (swapped QK^T, lane-local
// softmax, P-overlay-on-Q, swizzled staging); only geometry changed:
//   - each K/V tile staged ONCE per 128 q-rows (was per 64) -> VMEM
//     requests and KV L2 re-reads halve; barriers per unit work halve.
//   - per-thread prefetch: 2 gload16/kt (512 threads cover K+V tile).
//   - LDS: Q/P 16K + K 2x8K + V 2x8K = 48 KB -> 2 blocks/CU x 8 waves
//     = 16 waves/CU (same occupancy as R5, half the staging duty).
// Grid (NCTX/128, H, B) = (8, 16, 4).
// ---------------------------------------------------------------------------
__global__ __launch_bounds__(512) void attn_mfma(
    const f16* __restrict__ Qp, long long sQb, int ldq,
    const f16* __restrict__ Kp, long long sKb, int ldk,
    const f16* __restrict__ Vt, f16* __restrict__ O, long long sOb) {
  __shared__ f16 QP[8192];  // 128 x 64 Q staging; reused as P per-wave
  __shared__ f16 Ks[2][4096];
  __shared__ f16 Vs[2][4096];
  const int tid = threadIdx.x, wave = tid >> 6, lane = tid & 63;
  const int quad = lane >> 4, m16 = lane & 15;
  const int q0 = blockIdx.x * 128, h = blockIdx.y, b = blockIdx.z;
  const f16* Qb = Qp + (long long)b * sQb + h * 64;
  const f16* Kb = Kp + (long long)b * sKb + h * 64;
  const f16* Vb = Vt + (size_t)(b * H_ + h) * 64 * 1024;

  // Coalesced staging geometry (512 threads): row = tid>>3 (0..63),
  // chunk slot = tid&7, source chunk pre-swizzled by ^(row&7).
  const int rowS = tid >> 3;                     // 0..63
  const int kkc = ((tid & 7) ^ (rowS & 7)) * 8;  // pre-swizzled source chunk
  const int lB = tid * 8;                        // linear LDS dest (f16)

  // Prologue: Q (2 loads: rows rowS, rowS+64) then K0/V0 (1 load each).
#pragma unroll
  for (int j = 0; j < 2; ++j)
    gload16(Qb + (size_t)(q0 + j * 64 + rowS) * ldq + kkc,
            &QP[j * 4096 + lB]);
  gload16(Kb + (size_t)rowS * ldk + kkc, &Ks[0][lB]);
  gload16(Vb + (size_t)rowS * 1024 + kkc, &Vs[0][lB]);

  float m_run = -1e30f, l_run = 0.f;
  f32x4 Oa[4];
  const f32x4 z = {0.f, 0.f, 0.f, 0.f};
#pragma unroll
  for (int j = 0; j < 4; ++j) Oa[j] = z;

  // Wait own Q loads (oldest 2 of 4 outstanding), barrier -> all Q in.
  asm volatile("s_waitcnt vmcnt(2)" ::: "memory");
  __builtin_amdgcn_s_barrier();

  // Hoisted Q fragments (B-operand: n = q = m16); wave owns rows
  // [wave*16, wave*16+16).
  const int c0 = (quad ^ (m16 & 7)) * 8;
  const int c1 = ((quad + 4) ^ (m16 & 7)) * 8;
  const f16x8 qf0 = *(const f16x8*)&QP[(wave * 16 + m16) * 64 + c0];
  const f16x8 qf1 = *(const f16x8*)&QP[(wave * 16 + m16) * 64 + c1];

  // Wave-private P tile (16 q x 64 kv) overlays this wave's own Q rows.
  f16* Pw = QP + wave * 1024;

  for (int kt = 0; kt < 16; ++kt) {
    const int cur = kt & 1;
    if (kt < 15) {
      gload16(Kb + (size_t)((kt + 1) * 64 + rowS) * ldk + kkc,
              &Ks[cur ^ 1][lB]);
      gload16(Vb + (size_t)rowS * 1024 + (kt + 1) * 64 + kkc,
              &Vs[cur ^ 1][lB]);
      asm volatile("s_waitcnt vmcnt(2)" ::: "memory");  // tile kt landed
    } else {
      asm volatile("s_waitcnt vmcnt(0)" ::: "memory");
    }
    __builtin_amdgcn_s_barrier();

    // Swapped QK^T: lane holds S^T[kv = jn*16 + quad*4 + r][q = m16].
    f32x4 S[4];
    __builtin_amdgcn_s_setprio(1);
#pragma unroll
    for (int jn = 0; jn < 4; ++jn) {
      S[jn] = z;
      const f16x8 kf0 = *(const f16x8*)&Ks[cur][(jn * 16 + m16) * 64 + c0];
      const f16x8 kf1 = *(const f16x8*)&Ks[cur][(jn * 16 + m16) * 64 + c1];
      S[jn] = __builtin_amdgcn_mfma_f32_16x16x32_f16(kf0, qf0, S[jn], 0, 0, 0);
      S[jn] = __builtin_amdgcn_mfma_f32_16x16x32_f16(kf1, qf1, S[jn], 0, 0, 0);
    }
    __builtin_amdgcn_s_setprio(0);

    // Row max: 15 in-lane fmax + 2 shfl_xor.
    float mv0 = fmaxf(fmaxf(S[0][0], S[1][0]), fmaxf(S[2][0], S[3][0]));
    float mv1 = fmaxf(fmaxf(S[0][1], S[1][1]), fmaxf(S[2][1], S[3][1]));
    float mv2 = fmaxf(fmaxf(S[0][2], S[1][2]), fmaxf(S[2][2], S[3][2]));
    float mv3 = fmaxf(fmaxf(S[0][3], S[1][3]), fmaxf(S[2][3], S[3][3]));
    float mx = fmaxf(fmaxf(mv0, mv1), fmaxf(mv2, mv3));
    mx = fmaxf(mx, __shfl_xor(mx, 16, 64));
    mx = fmaxf(mx, __shfl_xor(mx, 32, 64));
    mx *= 0.125f;
    const float mnew = fmaxf(m_run, mx);
    const float al = __expf(m_run - mnew);
    m_run = mnew;

    // P = exp(S*0.125 - mnew); pack 4 f16 -> one b64 per jn (swizzled).
    float rs = 0.f;
#pragma unroll
    for (int jn = 0; jn < 4; ++jn) {
      P4 p4;
#pragma unroll
      for (int r = 0; r < 4; ++r) {
        const float p = __expf(__builtin_fmaf(S[jn][r], 0.125f, -mnew));
        rs += p;
        p4.h[r] = (f16)p;
      }
      *(ushort4*)&Pw[m16 * 64 + (((jn * 2 + (quad >> 1)) ^ (m16 & 7)) * 8) +
                     (quad & 1) * 4] = p4.u;
    }
    rs += __shfl_xor(rs, 16, 64);
    rs += __shfl_xor(rs, 32, 64);
    l_run = l_run * al + rs;

    // Broadcast al into the PV output domain q = quad*4 + r.
    float alq[4];
#pragma unroll
    for (int r = 0; r < 4; ++r) alq[r] = __shfl(al, quad * 4 + r, 64);
#pragma unroll
    for (int j = 0; j < 4; ++j) {
      Oa[j][0] *= alq[0];
      Oa[j][1] *= alq[1];
      Oa[j][2] *= alq[2];
      Oa[j][3] *= alq[3];
    }

    // PV: A = P[q=m16][kv chunk quad] (swizzled read), B = V^T.
    const f16x8 pf0 = *(const f16x8*)&Pw[m16 * 64 + c0];
    const f16x8 pf1 = *(const f16x8*)&Pw[m16 * 64 + c1];
    __builtin_amdgcn_s_setprio(1);
#pragma unroll
    for (int jd = 0; jd < 4; ++jd) {
      const f16x8 vf0 = *(const f16x8*)&Vs[cur][(jd * 16 + m16) * 64 + c0];
      const f16x8 vf1 = *(const f16x8*)&Vs[cur][(jd * 16 + m16) * 64 + c1];
      Oa[jd] = __builtin_amdgcn_mfma_f32_16x16x32_f16(pf0, vf0, Oa[jd], 0, 0, 0);
      Oa[jd] = __builtin_amdgcn_mfma_f32_16x16x32_f16(pf1, vf1, Oa[jd], 0, 0, 0);
    }
    __builtin_amdgcn_s_setprio(0);
    __builtin_amdgcn_s_barrier();
  }

  // l broadcast into output domain, then scale + store.
  float lq[4];
#pragma unroll
  for (int r = 0; r < 4; ++r) lq[r] = 1.0f / __shfl(l_run, quad * 4 + r, 64);
#pragma unroll
  for (int jd = 0; jd < 4; ++jd)
#pragma unroll
    for (int r = 0; r < 4; ++r) {
      const float v = Oa[jd][r] * lq[r];
      const size_t off = (long long)b * sOb +
                         (size_t)(q0 + wave * 16 + quad * 4 + r) * D_ + h * 64 +
                         jd * 16 + m16;
      O[off] = (f16)v;
    }
}

// ---------------------------------------------------------------------------
extern "C" void kernel_launch(void* const* d_in, const int* in_sizes, int n_in,
                              void* d_out, int out_size, void* d_ws,
                              size_t ws_size, hipStream_t stream) {
  const float* x = (const float*)d_in[0];
  const float* coords = (const float*)d_in[1];
  const unsigned char* isctx = (const unsigned char*)d_in[2];
  const float* rope = (const float*)d_in[3];
  const float* ctx_in_w = (const float*)d_in[4];
  const float* ctx_in_b = (const float*)d_in[5];
  const float* ctx_out_w = (const float*)d_in[6];
  const float* ctx_out_b = (const float*)d_in[7];
  const float* tgt_in_w = (const float*)d_in[8];
  const float* tgt_in_b = (const float*)d_in[9];
  const float* tgt_out_w = (const float*)d_in[10];
  const float* tgt_out_b = (const float*)d_in[11];
  float* out = (float*)d_out;

  // ws layout (f16 units): tok 8M | wcat 8M | qkvc 12M | kvt 8M | qt 4M |
  // vt 4M | pos/ipos ints
  f16* ws = (f16*)d_ws;
  f16* tok = ws;
  f16* wcat = tok + 8388608;
  f16* qkvc = wcat + 8388608;
  f16* kvt = qkvc + 12582912;
  f16* qt = kvt + 8388608;
  f16* vt = qt + 4194304;
  int* pos = (int*)(vt + 4194304);
  int* ipos = pos + B_ * K_;

  partition_kernel<<<B_, 256, 0, stream>>>(isctx, pos, ipos);
  cvt_all<<<8192, 256, 0, stream>>>(ctx_in_w, tgt_in_w, ctx_out_w, tgt_out_w,
                                    wcat);
  rope_kernel<<<B_ * K_, 256, 0, stream>>>(x, coords, rope, ipos, tok);

  // Merged projection: ctx QKV + tgt KV + tgt Q in one dispatch.
  gemm_proj<<<dim3(48, 8, B_), 256, 0, stream>>>(tok, wcat, ctx_in_b,
                                                 tgt_in_b, qkvc, kvt, qt);

  // ctx self-attention (output overwrites tok rows 0..1023)
  vtrans_kernel<<<dim3(16, H_, B_), 256, 0, stream>>>(
      (const ushort_t*)qkvc, (long long)NCTX_ * 3 * D_, 3 * D_, 2 * D_,
      (ushort_t*)vt);
  attn_mfma<<<dim3(8, H_, B_), 512, 0, stream>>>(
      qkvc, (long long)NCTX_ * 3 * D_, 3 * D_, qkvc + D_,
      (long long)NCTX_ * 3 * D_, 3 * D_, vt, tok, (long long)K_ * D_);
  // tgt cross-attention
  vtrans_kernel<<<dim3(16, H_, B_), 256, 0, stream>>>(
      (const ushort_t*)kvt, (long long)NCTX_ * 2 * D_, 2 * D_, D_,
      (ushort_t*)vt);
  attn_mfma<<<dim3(8, H_, B_), 512, 0, stream>>>(
      qt, (long long)NCTX_ * D_, D_, kvt, (long long)NCTX_ * 2 * D_, 2 * D_,
      vt, tok + (size_t)NCTX_ * D_, (long long)K_ * D_);

  // Merged output projections (fp32, scattered to original order)
  gemm_out<<<dim3(8, 8, 2 * B_), 256, 0, stream>>>(
      tok, wcat + 6291456, ctx_out_b, tgt_out_b, ipos, out);
}

// Round 7
// 285.986 us; speedup vs baseline: 1.2570x; 1.0625x over previous
//
#include <hip/hip_runtime.h>
#include <math.h>

#define B_    4
#define K_    2048
#define D_    1024
#define H_    16
#define NCTX_ 1024

typedef unsigned short ushort_t;
typedef _Float16 f16;
typedef __attribute__((ext_vector_type(8))) _Float16 f16x8;
typedef __attribute__((ext_vector_type(4))) float f32x4;

union U4 {
  f16 h[4];
  ushort4 u;
};

union P4 {
  f16 h[4];
  ushort4 u;  // 8 bytes -> one ds_write_b64 / global 8B store
};

__device__ __forceinline__ void gload16(const void* g, void* l) {
  __builtin_amdgcn_global_load_lds(
      (const __attribute__((address_space(1))) unsigned int*)g,
      (__attribute__((address_space(3))) unsigned int*)l, 16, 0, 0);
}

// ---------------------------------------------------------------------------
// Kernel 1: partition scan (verified R1-R4).
// ---------------------------------------------------------------------------
__global__ __launch_bounds__(256) void partition_kernel(
    const unsigned char* __restrict__ isctx, int* __restrict__ pos,
    int* __restrict__ ipos) {
  const int b = blockIdx.x;
  const int tid = threadIdx.x;
  const int wid = tid >> 6, lane = tid & 63;
  __shared__ int csum[4];
  __shared__ int waveTot[4];
  __shared__ int strideSh;

  int cnt = 0;
  for (int i = 0; i < 32; ++i) cnt += (isctx[tid * 32 + i] != 0);
  for (int off = 32; off; off >>= 1) cnt += __shfl_down(cnt, off, 64);
  if (lane == 0) csum[wid] = cnt;
  __syncthreads();
  if (tid == 0) {
    int t = csum[0] + csum[1] + csum[2] + csum[3];
    strideSh = (t > 2048) ? 1 : ((t > 768) ? 4 : 8);
  }
  __syncthreads();
  const int stride = strideSh;

  const unsigned char* base = isctx + (size_t)b * K_ * stride;
  int f[8];
  int s = 0;
  for (int i = 0; i < 8; ++i) {
    f[i] = base[(size_t)(tid * 8 + i) * stride] != 0;
    s += f[i];
  }
  int inc = s;
  for (int off = 1; off < 64; off <<= 1) {
    int v = __shfl_up(inc, off, 64);
    if (lane >= off) inc += v;
  }
  if (lane == 63) waveTot[wid] = inc;
  __syncthreads();
  int wOff = 0;
  for (int w = 0; w < wid; ++w) wOff += waveTot[w];
  int run = wOff + inc - s;
  for (int i = 0; i < 8; ++i) {
    int k = tid * 8 + i;
    int p;
    if (f[i]) {
      p = run;
      run++;
    } else {
      p = NCTX_ + k - run;
    }
    pos[b * K_ + k] = p;
    ipos[b * K_ + p] = k;
  }
}

// ---------------------------------------------------------------------------
// Kernel 2: RoPE + permute-gather -> f16 token buffer.
// ---------------------------------------------------------------------------
__global__ __launch_bounds__(256) void rope_kernel(
    const float* __restrict__ x, const float* __restrict__ coords,
    const float* __restrict__ cache, const int* __restrict__ ipos,
    f16* __restrict__ tok) {
  const int row = blockIdx.x;
  const int b = row >> 11;
  const int r = row & (K_ - 1);
  const int k = ipos[row];
  const int t = threadIdx.x;

  const float cy = coords[(size_t)(b * K_ + k) * 2 + 0];
  const float cx = coords[(size_t)(b * K_ + k) * 2 + 1];
  const int ypos = (int)fminf(fmaxf(cy / 224.0f * 1023.0f, 0.0f), 1023.0f);
  const int xpos = (int)fminf(fmaxf(cx / 224.0f * 1023.0f, 0.0f), 1023.0f);

  const float4 v = ((const float4*)(x + ((size_t)b * K_ + k) * D_))[t];
  const int e = 4 * t;
  const float* crow;
  int coff;
  if (e < 512) {
    crow = cache + (size_t)xpos * 512;
    coff = e;
  } else {
    crow = cache + (size_t)ypos * 512;
    coff = e - 512;
  }
  const float4 cs = *(const float4*)(crow + coff);
  float o[4];
  o[0] = v.x * cs.x - v.y * cs.y;
  o[1] = v.x * cs.y + v.y * cs.x;
  o[2] = v.z * cs.z - v.w * cs.w;
  o[3] = v.z * cs.w + v.w * cs.z;
  U4 h;
#pragma unroll
  for (int i = 0; i < 4; ++i) h.h[i] = (f16)o[i];
  ((ushort4*)(tok + ((size_t)b * K_ + r) * D_))[t] = h.u;
}

// ---------------------------------------------------------------------------
// Kernel 3: all weights fp32 -> f16, concatenated:
// [0,3M) ctx_in | [3M,5M) tgt_in kv | [5M,6M) tgt_in q | [6M,7M) ctx_out |
// [7M,8M) tgt_out   (M = 1048576 floats)
// ---------------------------------------------------------------------------
__global__ __launch_bounds__(256) void cvt_all(
    const float* __restrict__ ctx_in_w, const float* __restrict__ tgt_in_w,
    const float* __restrict__ ctx_out_w, const float* __restrict__ tgt_out_w,
    f16* __restrict__ dst) {
  const int i4 = blockIdx.x * 256 + threadIdx.x;  // 0..2097151
  const int f = i4 * 4;
  const float* src;
  if (f < 3145728) src = ctx_in_w + f;
  else if (f < 5242880) src = tgt_in_w + (f - 3145728 + 1048576);
  else if (f < 6291456) src = tgt_in_w + (f - 5242880);
  else if (f < 7340032) src = ctx_out_w + (f - 6291456);
  else src = tgt_out_w + (f - 7340032);
  const float4 v = *(const float4*)src;
  U4 u;
  u.h[0] = (f16)v.x;
  u.h[1] = (f16)v.y;
  u.h[2] = (f16)v.z;
  u.h[3] = (f16)v.w;
  ((ushort4*)dst)[i4] = u.u;
}

// ---------------------------------------------------------------------------
// GEMM core v3 (verified R3): coalesced staging (8-lane contiguous 128-B row
// segments), row-major [128][64] LDS with both-sides XOR swizzle, BK=64,
// double-buffered, counted vmcnt(8). gemm_proj 120 -> 75.8us, conflicts 0.
// ---------------------------------------------------------------------------
#define GEMM_PRE(AP, WP, Kd)                                                  \
  const int rb_ = wave * 8 + (lane >> 3);         /* row 0..31 (j adds 32) */ \
  const int kk_ = ((lane & 7) ^ (lane >> 3)) * 8; /* pre-swizzled k-chunk */  \
  const f16* gA_ = (AP) + (size_t)rb_ * (Kd) + kk_;                           \
  const f16* gW_ = (WP) + (size_t)rb_ * (Kd) + kk_;                           \
  const int lA_ = wave * 8 * 64 + lane * 8; /* == row*64 + kkchunk*8 */

#define GEMM_STAGE(k0s, bb)                                                   \
  _Pragma("unroll") for (int j = 0; j < 4; ++j) {                             \
    gload16(gA_ + (size_t)j * 32 * Kd_ + (k0s), &lds[(bb) + j * 2048 + lA_]); \
    gload16(gW_ + (size_t)j * 32 * Kd_ + (k0s),                               \
            &lds[(bb) + 8192 + j * 2048 + lA_]);                              \
  }

#define GEMM_TILE(bb)                                                         \
  _Pragma("unroll") for (int kh = 0; kh < 2; ++kh) {                          \
    f16x8 af[4], wf[4];                                                       \
    _Pragma("unroll") for (int i = 0; i < 4; ++i) {                           \
      const int ca = ((kh * 4 + quad) ^ (m16 & 7)) * 8;                       \
      af[i] = *(const f16x8*)&lds[(bb) + (wm + i * 16 + m16) * 64 + ca];      \
      wf[i] =                                                                 \
          *(const f16x8*)&lds[(bb) + 8192 + (wn + i * 16 + m16) * 64 + ca];   \
    }                                                                         \
    _Pragma("unroll") for (int i = 0; i < 4; ++i)                             \
        _Pragma("unroll") for (int j = 0; j < 4; ++j)                         \
      acc[i][j] = __builtin_amdgcn_mfma_f32_16x16x32_f16(af[i], wf[j],        \
                                                         acc[i][j], 0, 0, 0); \
  }

#define GEMM_CORE(AP, WP, Kd)                                                 \
  f32x4 acc[4][4];                                                            \
  {                                                                           \
    const f32x4 z = {0.f, 0.f, 0.f, 0.f};                                     \
    for (int i = 0; i < 4; ++i)                                               \
      for (int j = 0; j < 4; ++j) acc[i][j] = z;                              \
  }                                                                           \
  const int Kd_ = (Kd);                                                       \
  GEMM_PRE(AP, WP, Kd_)                                                       \
  GEMM_STAGE(0, 0)                                                            \
  for (int t = 0; t < Kd_ / 64; ++t) {                                        \
    const int cb = (t & 1) * 16384;                                           \
    if (t + 1 < Kd_ / 64) {                                                   \
      GEMM_STAGE((t + 1) * 64, ((t + 1) & 1) * 16384)                         \
      asm volatile("s_waitcnt vmcnt(8)" ::: "memory");                        \
    } else {                                                                  \
      asm volatile("s_waitcnt vmcnt(0)" ::: "memory");                        \
    }                                                                         \
    __builtin_amdgcn_s_barrier();                                             \
    asm volatile("" ::: "memory");                                            \
    GEMM_TILE(cb)                                                             \
    asm volatile("" ::: "memory");                                            \
    __builtin_amdgcn_s_barrier();                                             \
  }

// ---------------------------------------------------------------------------
// Kernel 4: merged projection GEMM. grid (48, 8, 4):
//   nb < 40: ctx rows x [ctx QK (2048) | ctx V (1024) | tgt K (1024) |
//            tgt V (1024)] -> qkvc / vtc^T / kvt / vtt^T
//   nb >= 40: tgt rows x tgt_in Q (1024) -> qt
// V strips are written TRANSPOSED (d-major, [b,h][d=64][kv=1024]) directly
// in the epilogue -> the vtrans kernels and their HBM round trip disappear.
// Per V strip: 4 consecutive kv (r) pack into one ushort4 (8B store); quads
// give 32B-contiguous segments per d-row.
// ---------------------------------------------------------------------------
__global__ __launch_bounds__(256, 2) void gemm_proj(
    const f16* __restrict__ tok, const f16* __restrict__ wcat,
    const float* __restrict__ ctx_in_b, const float* __restrict__ tgt_in_b,
    f16* __restrict__ qkvc, f16* __restrict__ kvt, f16* __restrict__ qt,
    f16* __restrict__ vtc, f16* __restrict__ vtt) {
  __shared__ f16 lds[32768];
  const int tid = threadIdx.x;
  const int wave = tid >> 6, lane = tid & 63;
  const int quad = lane >> 4, m16 = lane & 15;
  const int nb = blockIdx.x, mb = blockIdx.y, b = blockIdx.z;
  const int wm = (wave & 1) << 6, wn = (wave >> 1) << 6;
  const int m0 = mb * 128;
  const bool isQ = nb >= 40;
  const int n0 = isQ ? (nb - 40) * 128 : nb * 128;
  const f16* AP = tok + (size_t)b * K_ * D_ +
                  (isQ ? (size_t)NCTX_ * D_ : (size_t)0) + (size_t)m0 * D_;
  const f16* WP = wcat + (isQ ? (size_t)5242880 : (size_t)0) +
                  (size_t)n0 * D_;

  GEMM_CORE(AP, WP, D_)

#pragma unroll
  for (int j = 0; j < 4; ++j) {
    const int col = n0 + wn + j * 16 + m16;
    if (isQ) {
      const float bv = tgt_in_b[col];
      f16* dst = qt + (size_t)b * NCTX_ * 1024;
#pragma unroll
      for (int i = 0; i < 4; ++i) {
        const int mr = m0 + wm + i * 16 + quad * 4;
#pragma unroll
        for (int r = 0; r < 4; ++r)
          dst[(size_t)(mr + r) * 1024 + col] = (f16)(acc[i][j][r] + bv);
      }
    } else if (col < 2048) {
      // ctx Q,K -> qkvc (ld 2048)
      const float bv = ctx_in_b[col];
      f16* dst = qkvc + (size_t)b * NCTX_ * 2048;
#pragma unroll
      for (int i = 0; i < 4; ++i) {
        const int mr = m0 + wm + i * 16 + quad * 4;
#pragma unroll
        for (int r = 0; r < 4; ++r)
          dst[(size_t)(mr + r) * 2048 + col] = (f16)(acc[i][j][r] + bv);
      }
    } else if (col >= 3072 && col < 4096) {
      // tgt K -> kvt (ld 1024)
      const float bv = tgt_in_b[D_ + col - 3072];
      f16* dst = kvt + (size_t)b * NCTX_ * 1024;
      const int dcol = col - 3072;
#pragma unroll
      for (int i = 0; i < 4; ++i) {
        const int mr = m0 + wm + i * 16 + quad * 4;
#pragma unroll
        for (int r = 0; r < 4; ++r)
          dst[(size_t)(mr + r) * 1024 + dcol] = (f16)(acc[i][j][r] + bv);
      }
    } else {
      // V (ctx: 2048..3071 -> vtc; tgt: 4096..5119 -> vtt), transposed.
      const bool isCtxV = col < 3072;
      const int hd = isCtxV ? (col - 2048) : (col - 4096);  // h*64 + d
      const float bv = isCtxV ? ctx_in_b[col] : tgt_in_b[D_ + col - 3072];
      f16* dst = (isCtxV ? vtc : vtt) +
                 ((size_t)(b * H_ + (hd >> 6)) << 16) +
                 (size_t)(hd & 63) * 1024;
#pragma unroll
      for (int i = 0; i < 4; ++i) {
        const int mr = m0 + wm + i * 16 + quad * 4;  // kv base (mult of 4)
        P4 p4;
#pragma unroll
        for (int r = 0; r < 4; ++r) p4.h[r] = (f16)(acc[i][j][r] + bv);
        *(ushort4*)(dst + mr) = p4.u;
      }
    }
  }
}

// ---------------------------------------------------------------------------
// Kernel 5: merged output projections. grid (8, 8, 8): b = z&3, sel = z>>2.
// fp32 output scattered to original token order (16-lane 64B segments ->
// already fully coalesced).
// ---------------------------------------------------------------------------
__global__ __launch_bounds__(256, 2) void gemm_out(
    const f16* __restrict__ Atok, const f16* __restrict__ Wbase,
    const float* __restrict__ bias_ctx, const float* __restrict__ bias_tgt,
    const int* __restrict__ ipos, float* __restrict__ out) {
  __shared__ f16 lds[32768];
  const int tid = threadIdx.x;
  const int wave = tid >> 6, lane = tid & 63;
  const int quad = lane >> 4, m16 = lane & 15;
  const int n0 = blockIdx.x * 128, m0 = blockIdx.y * 128;
  const int b = blockIdx.z & 3, sel = blockIdx.z >> 2;
  const int wm = (wave & 1) << 6, wn = (wave >> 1) << 6;
  const f16* AP = Atok + (size_t)b * K_ * D_ + (size_t)sel * NCTX_ * D_ +
                  (size_t)m0 * D_;
  const f16* WP = Wbase + (size_t)sel * 1048576 + (size_t)n0 * D_;
  const float* bias = sel ? bias_tgt : bias_ctx;

  GEMM_CORE(AP, WP, D_)

#pragma unroll
  for (int j = 0; j < 4; ++j) {
    const int col = n0 + wn + j * 16 + m16;
    const float bv = bias[col];
#pragma unroll
    for (int i = 0; i < 4; ++i) {
      const int mr = m0 + wm + i * 16 + quad * 4;
#pragma unroll
      for (int r = 0; r < 4; ++r) {
        const int orow = ipos[b * K_ + sel * NCTX_ + mr + r];
        out[(size_t)b * K_ * D_ + (size_t)orow * D_ + col] =
            acc[i][j][r] + bv;
      }
    }
  }
}

// ---------------------------------------------------------------------------
// Kernel 6: MFMA flash attention v5 — ctx+tgt MERGED (grid z = 8: z<4 ctx
// b=z, z>=4 tgt b=z-4). Per-wave inner code identical to verified R6
// (swapped QK^T, lane-local softmax, P-overlay-on-Q, coalesced+swizzled
// dbuf staging, counted vmcnt). New: EXACT defer-rescale — when
// __all(mx <= m_run), al == 1 exactly -> skip Oa rescale + al broadcast
// (no numerical change). V read from vtc/vtt (written transposed by
// gemm_proj; vtrans eliminated).
// ---------------------------------------------------------------------------
__global__ __launch_bounds__(512) void attn_mfma(
    const f16* __restrict__ qkvc, const f16* __restrict__ kvt,
    const f16* __restrict__ qt, const f16* __restrict__ vtc,
    const f16* __restrict__ vtt, f16* __restrict__ O) {
  __shared__ f16 QP[8192];  // 128 x 64 Q staging; reused as P per-wave
  __shared__ f16 Ks[2][4096];
  __shared__ f16 Vs[2][4096];
  const int tid = threadIdx.x, wave = tid >> 6, lane = tid & 63;
  const int quad = lane >> 4, m16 = lane & 15;
  const int q0 = blockIdx.x * 128, h = blockIdx.y;
  const int zz = blockIdx.z;
  const int b = zz & 3;
  const bool isCtx = zz < 4;

  const f16* Qb;
  const f16* Kb;
  int ld;
  if (isCtx) {
    Qb = qkvc + (size_t)b * NCTX_ * 2048 + h * 64;
    Kb = Qb + 1024;
    ld = 2048;
  } else {
    Qb = qt + (size_t)b * NCTX_ * 1024 + h * 64;
    Kb = kvt + (size_t)b * NCTX_ * 1024 + h * 64;
    ld = 1024;
  }
  const f16* Vb = (isCtx ? vtc : vtt) + ((size_t)(b * H_ + h) << 16);
  f16* Ob = O + (size_t)b * K_ * D_ + (isCtx ? 0 : (size_t)NCTX_ * D_);

  // Coalesced staging geometry (512 threads): row = tid>>3 (0..63),
  // chunk slot = tid&7, source chunk pre-swizzled by ^(row&7).
  const int rowS = tid >> 3;                     // 0..63
  const int kkc = ((tid & 7) ^ (rowS & 7)) * 8;  // pre-swizzled source chunk
  const int lB = tid * 8;                        // linear LDS dest (f16)

  // Prologue: Q (2 loads: rows rowS, rowS+64) then K0/V0 (1 load each).
#pragma unroll
  for (int j = 0; j < 2; ++j)
    gload16(Qb + (size_t)(q0 + j * 64 + rowS) * ld + kkc, &QP[j * 4096 + lB]);
  gload16(Kb + (size_t)rowS * ld + kkc, &Ks[0][lB]);
  gload16(Vb + (size_t)rowS * 1024 + kkc, &Vs[0][lB]);

  float m_run = -1e30f, l_run = 0.f;
  f32x4 Oa[4];
  const f32x4 z = {0.f, 0.f, 0.f, 0.f};
#pragma unroll
  for (int j = 0; j < 4; ++j) Oa[j] = z;

  // Wait own Q loads (oldest 2 of 4 outstanding), barrier -> all Q in.
  asm volatile("s_waitcnt vmcnt(2)" ::: "memory");
  __builtin_amdgcn_s_barrier();

  // Hoisted Q fragments (B-operand: n = q = m16); wave owns rows
  // [wave*16, wave*16+16).
  const int c0 = (quad ^ (m16 & 7)) * 8;
  const int c1 = ((quad + 4) ^ (m16 & 7)) * 8;
  const f16x8 qf0 = *(const f16x8*)&QP[(wave * 16 + m16) * 64 + c0];
  const f16x8 qf1 = *(const f16x8*)&QP[(wave * 16 + m16) * 64 + c1];

  // Wave-private P tile (16 q x 64 kv) overlays this wave's own Q rows.
  f16* Pw = QP + wave * 1024;

  for (int kt = 0; kt < 16; ++kt) {
    const int cur = kt & 1;
    if (kt < 15) {
      gload16(Kb + (size_t)((kt + 1) * 64 + rowS) * ld + kkc,
              &Ks[cur ^ 1][lB]);
      gload16(Vb + (size_t)rowS * 1024 + (kt + 1) * 64 + kkc,
              &Vs[cur ^ 1][lB]);
      asm volatile("s_waitcnt vmcnt(2)" ::: "memory");  // tile kt landed
    } else {
      asm volatile("s_waitcnt vmcnt(0)" ::: "memory");
    }
    __builtin_amdgcn_s_barrier();

    // Swapped QK^T: lane holds S^T[kv = jn*16 + quad*4 + r][q = m16].
    f32x4 S[4];
    __builtin_amdgcn_s_setprio(1);
#pragma unroll
    for (int jn = 0; jn < 4; ++jn) {
      S[jn] = z;
      const f16x8 kf0 = *(const f16x8*)&Ks[cur][(jn * 16 + m16) * 64 + c0];
      const f16x8 kf1 = *(const f16x8*)&Ks[cur][(jn * 16 + m16) * 64 + c1];
      S[jn] = __builtin_amdgcn_mfma_f32_16x16x32_f16(kf0, qf0, S[jn], 0, 0, 0);
      S[jn] = __builtin_amdgcn_mfma_f32_16x16x32_f16(kf1, qf1, S[jn], 0, 0, 0);
    }
    __builtin_amdgcn_s_setprio(0);

    // Row max: 15 in-lane fmax + 2 shfl_xor.
    float mv0 = fmaxf(fmaxf(S[0][0], S[1][0]), fmaxf(S[2][0], S[3][0]));
    float mv1 = fmaxf(fmaxf(S[0][1], S[1][1]), fmaxf(S[2][1], S[3][1]));
    float mv2 = fmaxf(fmaxf(S[0][2], S[1][2]), fmaxf(S[2][2], S[3][2]));
    float mv3 = fmaxf(fmaxf(S[0][3], S[1][3]), fmaxf(S[2][3], S[3][3]));
    float mx = fmaxf(fmaxf(mv0, mv1), fmaxf(mv2, mv3));
    mx = fmaxf(mx, __shfl_xor(mx, 16, 64));
    mx = fmaxf(mx, __shfl_xor(mx, 32, 64));
    mx *= 0.125f;

    // EXACT defer-rescale: if no lane's max grew, al == 1 -> skip rescale.
    const bool grow = !__all(mx <= m_run);
    float al = 1.f;
    if (grow) {
      const float mnew = fmaxf(m_run, mx);
      al = __expf(m_run - mnew);
      m_run = mnew;
    }

    // P = exp(S*0.125 - m_run); pack 4 f16 -> one b64 per jn (swizzled).
    float rs = 0.f;
#pragma unroll
    for (int jn = 0; jn < 4; ++jn) {
      P4 p4;
#pragma unroll
      for (int r = 0; r < 4; ++r) {
        const float p = __expf(__builtin_fmaf(S[jn][r], 0.125f, -m_run));
        rs += p;
        p4.h[r] = (f16)p;
      }
      *(ushort4*)&Pw[m16 * 64 + (((jn * 2 + (quad >> 1)) ^ (m16 & 7)) * 8) +
                     (quad & 1) * 4] = p4.u;
    }
    rs += __shfl_xor(rs, 16, 64);
    rs += __shfl_xor(rs, 32, 64);

    if (grow) {
      l_run = l_run * al + rs;
      // Broadcast al into the PV output domain q = quad*4 + r.
      float alq[4];
#pragma unroll
      for (int r = 0; r < 4; ++r) alq[r] = __shfl(al, quad * 4 + r, 64);
#pragma unroll
      for (int j = 0; j < 4; ++j) {
        Oa[j][0] *= alq[0];
        Oa[j][1] *= alq[1];
        Oa[j][2] *= alq[2];
        Oa[j][3] *= alq[3];
      }
    } else {
      l_run += rs;
    }

    // PV: A = P[q=m16][kv chunk quad] (swizzled read), B = V^T.
    const f16x8 pf0 = *(const f16x8*)&Pw[m16 * 64 + c0];
    const f16x8 pf1 = *(const f16x8*)&Pw[m16 * 64 + c1];
    __builtin_amdgcn_s_setprio(1);
#pragma unroll
    for (int jd = 0; jd < 4; ++jd) {
      const f16x8 vf0 = *(const f16x8*)&Vs[cur][(jd * 16 + m16) * 64 + c0];
      const f16x8 vf1 = *(const f16x8*)&Vs[cur][(jd * 16 + m16) * 64 + c1];
      Oa[jd] = __builtin_amdgcn_mfma_f32_16x16x32_f16(pf0, vf0, Oa[jd], 0, 0, 0);
      Oa[jd] = __builtin_amdgcn_mfma_f32_16x16x32_f16(pf1, vf1, Oa[jd], 0, 0, 0);
    }
    __builtin_amdgcn_s_setprio(0);
    __builtin_amdgcn_s_barrier();
  }

  // l broadcast into output domain, then scale + store.
  float lq[4];
#pragma unroll
  for (int r = 0; r < 4; ++r) lq[r] = 1.0f / __shfl(l_run, quad * 4 + r, 64);
#pragma unroll
  for (int jd = 0; jd < 4; ++jd)
#pragma unroll
    for (int r = 0; r < 4; ++r) {
      const float v = Oa[jd][r] * lq[r];
      const size_t off = (size_t)(q0 + wave * 16 + quad * 4 + r) * D_ +
                         h * 64 + jd * 16 + m16;
      Ob[off] = (f16)v;
    }
}

// ---------------------------------------------------------------------------
extern "C" void kernel_launch(void* const* d_in, const int* in_sizes, int n_in,
                              void* d_out, int out_size, void* d_ws,
                              size_t ws_size, hipStream_t stream) {
  const float* x = (const float*)d_in[0];
  const float* coords = (const float*)d_in[1];
  const unsigned char* isctx = (const unsigned char*)d_in[2];
  const float* rope = (const float*)d_in[3];
  const float* ctx_in_w = (const float*)d_in[4];
  const float* ctx_in_b = (const float*)d_in[5];
  const float* ctx_out_w = (const float*)d_in[6];
  const float* ctx_out_b = (const float*)d_in[7];
  const float* tgt_in_w = (const float*)d_in[8];
  const float* tgt_in_b = (const float*)d_in[9];
  const float* tgt_out_w = (const float*)d_in[10];
  const float* tgt_out_b = (const float*)d_in[11];
  float* out = (float*)d_out;

  // ws layout (f16 units): tok 8M | wcat 8M | qkvc 8M (ctx QK, ld2048) |
  // kvt 4M (tgt K) | qt 4M | vtc 4M | vtt 4M | pos/ipos ints  (= 80 MB)
  f16* ws = (f16*)d_ws;
  f16* tok = ws;
  f16* wcat = tok + 8388608;
  f16* qkvc = wcat + 8388608;
  f16* kvt = qkvc + 8388608;
  f16* qt = kvt + 4194304;
  f16* vtc = qt + 4194304;
  f16* vtt = vtc + 4194304;
  int* pos = (int*)(vtt + 4194304);
  int* ipos = pos + B_ * K_;

  partition_kernel<<<B_, 256, 0, stream>>>(isctx, pos, ipos);
  cvt_all<<<8192, 256, 0, stream>>>(ctx_in_w, tgt_in_w, ctx_out_w, tgt_out_w,
                                    wcat);
  rope_kernel<<<B_ * K_, 256, 0, stream>>>(x, coords, rope, ipos, tok);

  // Merged projection: ctx QK + ctx V^T + tgt K + tgt V^T + tgt Q.
  gemm_proj<<<dim3(48, 8, B_), 256, 0, stream>>>(
      tok, wcat, ctx_in_b, tgt_in_b, qkvc, kvt, qt, vtc, vtt);

  // Merged ctx+tgt flash attention (ctx output -> tok rows 0..1023,
  // tgt output -> tok rows 1024..2047).
  attn_mfma<<<dim3(8, H_, 2 * B_), 512, 0, stream>>>(qkvc, kvt, qt, vtc, vtt,
                                                     tok);

  // Merged output projections (fp32, scattered to original order)
  gemm_out<<<dim3(8, 8, 2 * B_), 256, 0, stream>>>(
      tok, wcat + 6291456, ctx_out_b, tgt_out_b, ipos, out);
}

// Round 9
// 278.766 us; speedup vs baseline: 1.2895x; 1.0259x over previous
//
#include <hip/hip_runtime.h>
#include <math.h>

#define B_    4
#define K_    2048
#define D_    1024
#define H_    16
#define NCTX_ 1024

typedef unsigned short ushort_t;
typedef _Float16 f16;
typedef __attribute__((ext_vector_type(8))) _Float16 f16x8;
typedef __attribute__((ext_vector_type(4))) float f32x4;

union U4 {
  f16 h[4];
  ushort4 u;
};

union P4 {
  f16 h[4];
  ushort4 u;  // 8 bytes -> one ds_write_b64 / global 8B store
};

__device__ __forceinline__ void gload16(const void* g, void* l) {
  __builtin_amdgcn_global_load_lds(
      (const __attribute__((address_space(1))) unsigned int*)g,
      (__attribute__((address_space(3))) unsigned int*)l, 16, 0, 0);
}

// ---------------------------------------------------------------------------
// Kernel 1: partition scan (verified R1-R4).
// ---------------------------------------------------------------------------
__global__ __launch_bounds__(256) void partition_kernel(
    const unsigned char* __restrict__ isctx, int* __restrict__ pos,
    int* __restrict__ ipos) {
  const int b = blockIdx.x;
  const int tid = threadIdx.x;
  const int wid = tid >> 6, lane = tid & 63;
  __shared__ int csum[4];
  __shared__ int waveTot[4];
  __shared__ int strideSh;

  int cnt = 0;
  for (int i = 0; i < 32; ++i) cnt += (isctx[tid * 32 + i] != 0);
  for (int off = 32; off; off >>= 1) cnt += __shfl_down(cnt, off, 64);
  if (lane == 0) csum[wid] = cnt;
  __syncthreads();
  if (tid == 0) {
    int t = csum[0] + csum[1] + csum[2] + csum[3];
    strideSh = (t > 2048) ? 1 : ((t > 768) ? 4 : 8);
  }
  __syncthreads();
  const int stride = strideSh;

  const unsigned char* base = isctx + (size_t)b * K_ * stride;
  int f[8];
  int s = 0;
  for (int i = 0; i < 8; ++i) {
    f[i] = base[(size_t)(tid * 8 + i) * stride] != 0;
    s += f[i];
  }
  int inc = s;
  for (int off = 1; off < 64; off <<= 1) {
    int v = __shfl_up(inc, off, 64);
    if (lane >= off) inc += v;
  }
  if (lane == 63) waveTot[wid] = inc;
  __syncthreads();
  int wOff = 0;
  for (int w = 0; w < wid; ++w) wOff += waveTot[w];
  int run = wOff + inc - s;
  for (int i = 0; i < 8; ++i) {
    int k = tid * 8 + i;
    int p;
    if (f[i]) {
      p = run;
      run++;
    } else {
      p = NCTX_ + k - run;
    }
    pos[b * K_ + k] = p;
    ipos[b * K_ + p] = k;
  }
}

// ---------------------------------------------------------------------------
// Kernel 2: RoPE + permute-gather -> f16 token buffer.
// ---------------------------------------------------------------------------
__global__ __launch_bounds__(256) void rope_kernel(
    const float* __restrict__ x, const float* __restrict__ coords,
    const float* __restrict__ cache, const int* __restrict__ ipos,
    f16* __restrict__ tok) {
  const int row = blockIdx.x;
  const int b = row >> 11;
  const int r = row & (K_ - 1);
  const int k = ipos[row];
  const int t = threadIdx.x;

  const float cy = coords[(size_t)(b * K_ + k) * 2 + 0];
  const float cx = coords[(size_t)(b * K_ + k) * 2 + 1];
  const int ypos = (int)fminf(fmaxf(cy / 224.0f * 1023.0f, 0.0f), 1023.0f);
  const int xpos = (int)fminf(fmaxf(cx / 224.0f * 1023.0f, 0.0f), 1023.0f);

  const float4 v = ((const float4*)(x + ((size_t)b * K_ + k) * D_))[t];
  const int e = 4 * t;
  const float* crow;
  int coff;
  if (e < 512) {
    crow = cache + (size_t)xpos * 512;
    coff = e;
  } else {
    crow = cache + (size_t)ypos * 512;
    coff = e - 512;
  }
  const float4 cs = *(const float4*)(crow + coff);
  float o[4];
  o[0] = v.x * cs.x - v.y * cs.y;
  o[1] = v.x * cs.y + v.y * cs.x;
  o[2] = v.z * cs.z - v.w * cs.w;
  o[3] = v.z * cs.w + v.w * cs.z;
  U4 h;
#pragma unroll
  for (int i = 0; i < 4; ++i) h.h[i] = (f16)o[i];
  ((ushort4*)(tok + ((size_t)b * K_ + r) * D_))[t] = h.u;
}

// ---------------------------------------------------------------------------
// Kernel 3: all weights fp32 -> f16, concatenated:
// [0,3M) ctx_in | [3M,5M) tgt_in kv | [5M,6M) tgt_in q | [6M,7M) ctx_out |
// [7M,8M) tgt_out   (M = 1048576 floats)
// ---------------------------------------------------------------------------
__global__ __launch_bounds__(256) void cvt_all(
    const float* __restrict__ ctx_in_w, const float* __restrict__ tgt_in_w,
    const float* __restrict__ ctx_out_w, const float* __restrict__ tgt_out_w,
    f16* __restrict__ dst) {
  const int i4 = blockIdx.x * 256 + threadIdx.x;  // 0..2097151
  const int f = i4 * 4;
  const float* src;
  if (f < 3145728) src = ctx_in_w + f;
  else if (f < 5242880) src = tgt_in_w + (f - 3145728 + 1048576);
  else if (f < 6291456) src = tgt_in_w + (f - 5242880);
  else if (f < 7340032) src = ctx_out_w + (f - 6291456);
  else src = tgt_out_w + (f - 7340032);
  const float4 v = *(const float4*)src;
  U4 u;
  u.h[0] = (f16)v.x;
  u.h[1] = (f16)v.y;
  u.h[2] = (f16)v.z;
  u.h[3] = (f16)v.w;
  ((ushort4*)dst)[i4] = u.u;
}

// ---------------------------------------------------------------------------
// GEMM core v3 (verified R3): coalesced staging (8-lane contiguous 128-B row
// segments), row-major [128][64] LDS with both-sides XOR swizzle, BK=64,
// double-buffered, counted vmcnt(8). gemm_proj 120 -> 75.8us, conflicts 0.
// ---------------------------------------------------------------------------
#define GEMM_PRE(AP, WP, Kd)                                                  \
  const int rb_ = wave * 8 + (lane >> 3);         /* row 0..31 (j adds 32) */ \
  const int kk_ = ((lane & 7) ^ (lane >> 3)) * 8; /* pre-swizzled k-chunk */  \
  const f16* gA_ = (AP) + (size_t)rb_ * (Kd) + kk_;                           \
  const f16* gW_ = (WP) + (size_t)rb_ * (Kd) + kk_;                           \
  const int lA_ = wave * 8 * 64 + lane * 8; /* == row*64 + kkchunk*8 */

#define GEMM_STAGE(k0s, bb)                                                   \
  _Pragma("unroll") for (int j = 0; j < 4; ++j) {                             \
    gload16(gA_ + (size_t)j * 32 * Kd_ + (k0s), &lds[(bb) + j * 2048 + lA_]); \
    gload16(gW_ + (size_t)j * 32 * Kd_ + (k0s),                               \
            &lds[(bb) + 8192 + j * 2048 + lA_]);                              \
  }

#define GEMM_TILE(bb)                                                         \
  _Pragma("unroll") for (int kh = 0; kh < 2; ++kh) {                          \
    f16x8 af[4], wf[4];                                                       \
    _Pragma("unroll") for (int i = 0; i < 4; ++i) {                           \
      const int ca = ((kh * 4 + quad) ^ (m16 & 7)) * 8;                       \
      af[i] = *(const f16x8*)&lds[(bb) + (wm + i * 16 + m16) * 64 + ca];      \
      wf[i] =                                                                 \
          *(const f16x8*)&lds[(bb) + 8192 + (wn + i * 16 + m16) * 64 + ca];   \
    }                                                                         \
    _Pragma("unroll") for (int i = 0; i < 4; ++i)                             \
        _Pragma("unroll") for (int j = 0; j < 4; ++j)                         \
      acc[i][j] = __builtin_amdgcn_mfma_f32_16x16x32_f16(af[i], wf[j],        \
                                                         acc[i][j], 0, 0, 0); \
  }

#define GEMM_CORE(AP, WP, Kd)                                                 \
  f32x4 acc[4][4];                                                            \
  {                                                                           \
    const f32x4 z = {0.f, 0.f, 0.f, 0.f};                                     \
    for (int i = 0; i < 4; ++i)                                               \
      for (int j = 0; j < 4; ++j) acc[i][j] = z;                              \
  }                                                                           \
  const int Kd_ = (Kd);                                                       \
  GEMM_PRE(AP, WP, Kd_)                                                       \
  GEMM_STAGE(0, 0)                                                            \
  for (int t = 0; t < Kd_ / 64; ++t) {                                        \
    const int cb = (t & 1) * 16384;                                           \
    if (t + 1 < Kd_ / 64) {                                                   \
      GEMM_STAGE((t + 1) * 64, ((t + 1) & 1) * 16384)                         \
      asm volatile("s_waitcnt vmcnt(8)" ::: "memory");                        \
    } else {                                                                  \
      asm volatile("s_waitcnt vmcnt(0)" ::: "memory");                        \
    }                                                                         \
    __builtin_amdgcn_s_barrier();                                             \
    asm volatile("" ::: "memory");                                            \
    GEMM_TILE(cb)                                                             \
    asm volatile("" ::: "memory");                                            \
    __builtin_amdgcn_s_barrier();                                             \
  }

// ---------------------------------------------------------------------------
// Kernel 4: merged projection GEMM. grid (48, 8, 4):
//   nb < 40: ctx rows x [ctx QK (2048) | ctx V (1024) | tgt K (1024) |
//            tgt V (1024)] -> qkvc / vtc^T / kvt / vtt^T
//   nb >= 40: tgt rows x tgt_in Q (1024) -> qt
// V strips written TRANSPOSED directly in the epilogue (verified R7).
// ---------------------------------------------------------------------------
__global__ __launch_bounds__(256, 2) void gemm_proj(
    const f16* __restrict__ tok, const f16* __restrict__ wcat,
    const float* __restrict__ ctx_in_b, const float* __restrict__ tgt_in_b,
    f16* __restrict__ qkvc, f16* __restrict__ kvt, f16* __restrict__ qt,
    f16* __restrict__ vtc, f16* __restrict__ vtt) {
  __shared__ f16 lds[32768];
  const int tid = threadIdx.x;
  const int wave = tid >> 6, lane = tid & 63;
  const int quad = lane >> 4, m16 = lane & 15;
  const int nb = blockIdx.x, mb = blockIdx.y, b = blockIdx.z;
  const int wm = (wave & 1) << 6, wn = (wave >> 1) << 6;
  const int m0 = mb * 128;
  const bool isQ = nb >= 40;
  const int n0 = isQ ? (nb - 40) * 128 : nb * 128;
  const f16* AP = tok + (size_t)b * K_ * D_ +
                  (isQ ? (size_t)NCTX_ * D_ : (size_t)0) + (size_t)m0 * D_;
  const f16* WP = wcat + (isQ ? (size_t)5242880 : (size_t)0) +
                  (size_t)n0 * D_;

  GEMM_CORE(AP, WP, D_)

#pragma unroll
  for (int j = 0; j < 4; ++j) {
    const int col = n0 + wn + j * 16 + m16;
    if (isQ) {
      const float bv = tgt_in_b[col];
      f16* dst = qt + (size_t)b * NCTX_ * 1024;
#pragma unroll
      for (int i = 0; i < 4; ++i) {
        const int mr = m0 + wm + i * 16 + quad * 4;
#pragma unroll
        for (int r = 0; r < 4; ++r)
          dst[(size_t)(mr + r) * 1024 + col] = (f16)(acc[i][j][r] + bv);
      }
    } else if (col < 2048) {
      // ctx Q,K -> qkvc (ld 2048)
      const float bv = ctx_in_b[col];
      f16* dst = qkvc + (size_t)b * NCTX_ * 2048;
#pragma unroll
      for (int i = 0; i < 4; ++i) {
        const int mr = m0 + wm + i * 16 + quad * 4;
#pragma unroll
        for (int r = 0; r < 4; ++r)
          dst[(size_t)(mr + r) * 2048 + col] = (f16)(acc[i][j][r] + bv);
      }
    } else if (col >= 3072 && col < 4096) {
      // tgt K -> kvt (ld 1024)
      const float bv = tgt_in_b[D_ + col - 3072];
      f16* dst = kvt + (size_t)b * NCTX_ * 1024;
      const int dcol = col - 3072;
#pragma unroll
      for (int i = 0; i < 4; ++i) {
        const int mr = m0 + wm + i * 16 + quad * 4;
#pragma unroll
        for (int r = 0; r < 4; ++r)
          dst[(size_t)(mr + r) * 1024 + dcol] = (f16)(acc[i][j][r] + bv);
      }
    } else {
      // V (ctx: 2048..3071 -> vtc; tgt: 4096..5119 -> vtt), transposed.
      const bool isCtxV = col < 3072;
      const int hd = isCtxV ? (col - 2048) : (col - 4096);  // h*64 + d
      const float bv = isCtxV ? ctx_in_b[col] : tgt_in_b[D_ + col - 3072];
      f16* dst = (isCtxV ? vtc : vtt) +
                 ((size_t)(b * H_ + (hd >> 6)) << 16) +
                 (size_t)(hd & 63) * 1024;
#pragma unroll
      for (int i = 0; i < 4; ++i) {
        const int mr = m0 + wm + i * 16 + quad * 4;  // kv base (mult of 4)
        P4 p4;
#pragma unroll
        for (int r = 0; r < 4; ++r) p4.h[r] = (f16)(acc[i][j][r] + bv);
        *(ushort4*)(dst + mr) = p4.u;
      }
    }
  }
}

// ---------------------------------------------------------------------------
// Kernel 5: merged output projections. grid (8, 8, 8): b = z&3, sel = z>>2.
// ---------------------------------------------------------------------------
__global__ __launch_bounds__(256, 2) void gemm_out(
    const f16* __restrict__ Atok, const f16* __restrict__ Wbase,
    const float* __restrict__ bias_ctx, const float* __restrict__ bias_tgt,
    const int* __restrict__ ipos, float* __restrict__ out) {
  __shared__ f16 lds[32768];
  const int tid = threadIdx.x;
  const int wave = tid >> 6, lane = tid & 63;
  const int quad = lane >> 4, m16 = lane & 15;
  const int n0 = blockIdx.x * 128, m0 = blockIdx.y * 128;
  const int b = blockIdx.z & 3, sel = blockIdx.z >> 2;
  const int wm = (wave & 1) << 6, wn = (wave >> 1) << 6;
  const f16* AP = Atok + (size_t)b * K_ * D_ + (size_t)sel * NCTX_ * D_ +
                  (size_t)m0 * D_;
  const f16* WP = Wbase + (size_t)sel * 1048576 + (size_t)n0 * D_;
  const float* bias = sel ? bias_tgt : bias_ctx;

  GEMM_CORE(AP, WP, D_)

#pragma unroll
  for (int j = 0; j < 4; ++j) {
    const int col = n0 + wn + j * 16 + m16;
    const float bv = bias[col];
#pragma unroll
    for (int i = 0; i < 4; ++i) {
      const int mr = m0 + wm + i * 16 + quad * 4;
#pragma unroll
      for (int r = 0; r < 4; ++r) {
        const int orow = ipos[b * K_ + sel * NCTX_ + mr + r];
        out[(size_t)b * K_ * D_ + (size_t)orow * D_ + col] =
            acc[i][j][r] + bv;
      }
    }
  }
}

// ---------------------------------------------------------------------------
// Kernel 6: MFMA flash attention v6 (resubmission of R8 — container-level
// infra failure, hazard audit clean). Changes vs verified R7 (inner math
// identical):
//  (a) 3-buffer K/V rotation (24 KB) instead of 2x dbuf (32 KB): per kt,
//      K@X[(2kt)%3], V@X[(2kt+1)%3]. K[kt+1] staged after barrier A into
//      V[kt-1]'s dead buffer; V[kt+1] staged after barrier B (post-QK^T)
//      into K[kt]'s dead buffer. Still 2 barriers/kt. LDS 48->40 KB ->
//      4 blocks/CU -> all 1024 blocks co-resident (was 768+256 tail).
//  (b) 1-D grid + XCD co-location decode: the 8 q-blocks sharing one
//      (h,z) KV set get the same id%8 -> same XCD -> per-XCD KV working
//      set = 16 x 256KB = 4MB = L2 (was 32MB -> thrash, FETCH 139MB).
// ---------------------------------------------------------------------------
__global__ __launch_bounds__(512) void attn_mfma(
    const f16* __restrict__ qkvc, const f16* __restrict__ kvt,
    const f16* __restrict__ qt, const f16* __restrict__ vtc,
    const f16* __restrict__ vtt, f16* __restrict__ O) {
  __shared__ f16 QP[8192];   // 128 x 64 Q staging; reused as P per-wave
  __shared__ f16 Xb[12288];  // 3 rotating 8KB K/V tile buffers
  const int tid = threadIdx.x, wave = tid >> 6, lane = tid & 63;
  const int quad = lane >> 4, m16 = lane & 15;

  // XCD co-location decode: id = (g%8) + 8*j + 64*(g/8), g = (h,z) pair.
  const int id = blockIdx.x;
  const int xcd = id & 7;
  const int t_ = id >> 3;
  const int j_ = t_ & 7;                 // q-block 0..7
  const int g = ((t_ >> 3) << 3) + xcd;  // 0..127
  const int h = g & 15;
  const int zz = g >> 4;
  const int b = zz & 3;
  const bool isCtx = zz < 4;
  const int q0 = j_ * 128;

  const f16* Qb;
  const f16* Kb;
  int ld;
  if (isCtx) {
    Qb = qkvc + (size_t)b * NCTX_ * 2048 + h * 64;
    Kb = Qb + 1024;
    ld = 2048;
  } else {
    Qb = qt + (size_t)b * NCTX_ * 1024 + h * 64;
    Kb = kvt + (size_t)b * NCTX_ * 1024 + h * 64;
    ld = 1024;
  }
  const f16* Vb = (isCtx ? vtc : vtt) + ((size_t)(b * H_ + h) << 16);
  f16* Ob = O + (size_t)b * K_ * D_ + (isCtx ? 0 : (size_t)NCTX_ * D_);

  // Coalesced staging geometry (512 threads): row = tid>>3 (0..63),
  // chunk slot = tid&7, source chunk pre-swizzled by ^(row&7).
  const int rowS = tid >> 3;                     // 0..63
  const int kkc = ((tid & 7) ^ (rowS & 7)) * 8;  // pre-swizzled source chunk
  const int lB = tid * 8;                        // linear LDS dest (f16)

  // Prologue: Q (2 loads), K[0] -> X0, V[0] -> X1.
#pragma unroll
  for (int j = 0; j < 2; ++j)
    gload16(Qb + (size_t)(q0 + j * 64 + rowS) * ld + kkc, &QP[j * 4096 + lB]);
  gload16(Kb + (size_t)rowS * ld + kkc, &Xb[lB]);
  gload16(Vb + (size_t)rowS * 1024 + kkc, &Xb[4096 + lB]);

  float m_run = -1e30f, l_run = 0.f;
  f32x4 Oa[4];
  const f32x4 z = {0.f, 0.f, 0.f, 0.f};
#pragma unroll
  for (int j = 0; j < 4; ++j) Oa[j] = z;

  asm volatile("s_waitcnt vmcnt(0)" ::: "memory");
  __builtin_amdgcn_s_barrier();

  // Hoisted Q fragments (B-operand: n = q = m16); wave owns rows
  // [wave*16, wave*16+16).
  const int c0 = (quad ^ (m16 & 7)) * 8;
  const int c1 = ((quad + 4) ^ (m16 & 7)) * 8;
  const f16x8 qf0 = *(const f16x8*)&QP[(wave * 16 + m16) * 64 + c0];
  const f16x8 qf1 = *(const f16x8*)&QP[(wave * 16 + m16) * 64 + c1];

  // Wave-private P tile (16 q x 64 kv) overlays this wave's own Q rows.
  f16* Pw = QP + wave * 1024;

  int xK = 0, xV = 4096;  // f16 offsets into Xb
  for (int kt = 0; kt < 16; ++kt) {
    int xKn = xK + 8192;
    if (xKn >= 12288) xKn -= 12288;

    // Barrier A: K[kt], V[kt] landed (issued >= half-iter ago -> no stall);
    // also orders PV(kt-1) of all waves before the K[kt+1] stage below.
    asm volatile("s_waitcnt vmcnt(0)" ::: "memory");
    __builtin_amdgcn_s_barrier();
    asm volatile("" ::: "memory");
    if (kt < 15)
      gload16(Kb + (size_t)((kt + 1) * 64 + rowS) * ld + kkc, &Xb[xKn + lB]);

    // Swapped QK^T: lane holds S^T[kv = jn*16 + quad*4 + r][q = m16].
    f32x4 S[4];
    __builtin_amdgcn_s_setprio(1);
#pragma unroll
    for (int jn = 0; jn < 4; ++jn) {
      S[jn] = z;
      const f16x8 kf0 = *(const f16x8*)&Xb[xK + (jn * 16 + m16) * 64 + c0];
      const f16x8 kf1 = *(const f16x8*)&Xb[xK + (jn * 16 + m16) * 64 + c1];
      S[jn] = __builtin_amdgcn_mfma_f32_16x16x32_f16(kf0, qf0, S[jn], 0, 0, 0);
      S[jn] = __builtin_amdgcn_mfma_f32_16x16x32_f16(kf1, qf1, S[jn], 0, 0, 0);
    }
    __builtin_amdgcn_s_setprio(0);

    // Barrier B: all waves' QK^T reads of K[kt] done -> its buffer is dead;
    // stage V[kt+1] into it (latency hidden under softmax+PV).
    __builtin_amdgcn_s_barrier();
    asm volatile("" ::: "memory");
    if (kt < 15)
      gload16(Vb + (size_t)rowS * 1024 + (kt + 1) * 64 + kkc, &Xb[xK + lB]);

    // Row max: 15 in-lane fmax + 2 shfl_xor.
    float mv0 = fmaxf(fmaxf(S[0][0], S[1][0]), fmaxf(S[2][0], S[3][0]));
    float mv1 = fmaxf(fmaxf(S[0][1], S[1][1]), fmaxf(S[2][1], S[3][1]));
    float mv2 = fmaxf(fmaxf(S[0][2], S[1][2]), fmaxf(S[2][2], S[3][2]));
    float mv3 = fmaxf(fmaxf(S[0][3], S[1][3]), fmaxf(S[2][3], S[3][3]));
    float mx = fmaxf(fmaxf(mv0, mv1), fmaxf(mv2, mv3));
    mx = fmaxf(mx, __shfl_xor(mx, 16, 64));
    mx = fmaxf(mx, __shfl_xor(mx, 32, 64));
    mx *= 0.125f;

    // EXACT defer-rescale: if no lane's max grew, al == 1 -> skip rescale.
    const bool grow = !__all(mx <= m_run);
    float al = 1.f;
    if (grow) {
      const float mnew = fmaxf(m_run, mx);
      al = __expf(m_run - mnew);
      m_run = mnew;
    }

    // P = exp(S*0.125 - m_run); pack 4 f16 -> one b64 per jn (swizzled).
    float rs = 0.f;
#pragma unroll
    for (int jn = 0; jn < 4; ++jn) {
      P4 p4;
#pragma unroll
      for (int r = 0; r < 4; ++r) {
        const float p = __expf(__builtin_fmaf(S[jn][r], 0.125f, -m_run));
        rs += p;
        p4.h[r] = (f16)p;
      }
      *(ushort4*)&Pw[m16 * 64 + (((jn * 2 + (quad >> 1)) ^ (m16 & 7)) * 8) +
                     (quad & 1) * 4] = p4.u;
    }
    rs += __shfl_xor(rs, 16, 64);
    rs += __shfl_xor(rs, 32, 64);

    if (grow) {
      l_run = l_run * al + rs;
      // Broadcast al into the PV output domain q = quad*4 + r.
      float alq[4];
#pragma unroll
      for (int r = 0; r < 4; ++r) alq[r] = __shfl(al, quad * 4 + r, 64);
#pragma unroll
      for (int j = 0; j < 4; ++j) {
        Oa[j][0] *= alq[0];
        Oa[j][1] *= alq[1];
        Oa[j][2] *= alq[2];
        Oa[j][3] *= alq[3];
      }
    } else {
      l_run += rs;
    }

    // PV: A = P[q=m16][kv chunk quad] (swizzled read), B = V^T.
    const f16x8 pf0 = *(const f16x8*)&Pw[m16 * 64 + c0];
    const f16x8 pf1 = *(const f16x8*)&Pw[m16 * 64 + c1];
    __builtin_amdgcn_s_setprio(1);
#pragma unroll
    for (int jd = 0; jd < 4; ++jd) {
      const f16x8 vf0 = *(const f16x8*)&Xb[xV + (jd * 16 + m16) * 64 + c0];
      const f16x8 vf1 = *(const f16x8*)&Xb[xV + (jd * 16 + m16) * 64 + c1];
      Oa[jd] = __builtin_amdgcn_mfma_f32_16x16x32_f16(pf0, vf0, Oa[jd], 0, 0, 0);
      Oa[jd] = __builtin_amdgcn_mfma_f32_16x16x32_f16(pf1, vf1, Oa[jd], 0, 0, 0);
    }
    __builtin_amdgcn_s_setprio(0);

    // Rotate: V[kt+1] sits in K[kt]'s old buffer; K[kt+1] in xKn.
    xV = xK;
    xK = xKn;
  }

  // l broadcast into output domain, then scale + store.
  float lq[4];
#pragma unroll
  for (int r = 0; r < 4; ++r) lq[r] = 1.0f / __shfl(l_run, quad * 4 + r, 64);
#pragma unroll
  for (int jd = 0; jd < 4; ++jd)
#pragma unroll
    for (int r = 0; r < 4; ++r) {
      const float v = Oa[jd][r] * lq[r];
      const size_t off = (size_t)(q0 + wave * 16 + quad * 4 + r) * D_ +
                         h * 64 + jd * 16 + m16;
      Ob[off] = (f16)v;
    }
}

// ---------------------------------------------------------------------------
extern "C" void kernel_launch(void* const* d_in, const int* in_sizes, int n_in,
                              void* d_out, int out_size, void* d_ws,
                              size_t ws_size, hipStream_t stream) {
  const float* x = (const float*)d_in[0];
  const float* coords = (const float*)d_in[1];
  const unsigned char* isctx = (const unsigned char*)d_in[2];
  const float* rope = (const float*)d_in[3];
  const float* ctx_in_w = (const float*)d_in[4];
  const float* ctx_in_b = (const float*)d_in[5];
  const float* ctx_out_w = (const float*)d_in[6];
  const float* ctx_out_b = (const float*)d_in[7];
  const float* tgt_in_w = (const float*)d_in[8];
  const float* tgt_in_b = (const float*)d_in[9];
  const float* tgt_out_w = (const float*)d_in[10];
  const float* tgt_out_b = (const float*)d_in[11];
  float* out = (float*)d_out;

  // ws layout (f16 units): tok 8M | wcat 8M | qkvc 8M (ctx QK, ld2048) |
  // kvt 4M (tgt K) | qt 4M | vtc 4M | vtt 4M | pos/ipos ints  (= 80 MB)
  f16* ws = (f16*)d_ws;
  f16* tok = ws;
  f16* wcat = tok + 8388608;
  f16* qkvc = wcat + 8388608;
  f16* kvt = qkvc + 8388608;
  f16* qt = kvt + 4194304;
  f16* vtc = qt + 4194304;
  f16* vtt = vtc + 4194304;
  int* pos = (int*)(vtt + 4194304);
  int* ipos = pos + B_ * K_;

  partition_kernel<<<B_, 256, 0, stream>>>(isctx, pos, ipos);
  cvt_all<<<8192, 256, 0, stream>>>(ctx_in_w, tgt_in_w, ctx_out_w, tgt_out_w,
                                    wcat);
  rope_kernel<<<B_ * K_, 256, 0, stream>>>(x, coords, rope, ipos, tok);

  // Merged projection: ctx QK + ctx V^T + tgt K + tgt V^T + tgt Q.
  gemm_proj<<<dim3(48, 8, B_), 256, 0, stream>>>(
      tok, wcat, ctx_in_b, tgt_in_b, qkvc, kvt, qt, vtc, vtt);

  // Merged ctx+tgt flash attention, 1-D grid with XCD co-location decode.
  attn_mfma<<<dim3(1024, 1, 1), 512, 0, stream>>>(qkvc, kvt, qt, vtc, vtt,
                                                  tok);

  // Merged output projections (fp32, scattered to original order)
  gemm_out<<<dim3(8, 8, 2 * B_), 256, 0, stream>>>(
      tok, wcat + 6291456, ctx_out_b, tgt_out_b, ipos, out);
}

// Round 10
// 274.811 us; speedup vs baseline: 1.3081x; 1.0144x over previous
//
#include <hip/hip_runtime.h>
#include <math.h>

#define B_    4
#define K_    2048
#define D_    1024
#define H_    16
#define NCTX_ 1024

typedef unsigned short ushort_t;
typedef _Float16 f16;
typedef __attribute__((ext_vector_type(8))) _Float16 f16x8;
typedef __attribute__((ext_vector_type(4))) float f32x4;

union U4 {
  f16 h[4];
  ushort4 u;
};

union P4 {
  f16 h[4];
  ushort4 u;  // 8 bytes -> one ds_write_b64 / global 8B store
};

__device__ __forceinline__ void gload16(const void* g, void* l) {
  __builtin_amdgcn_global_load_lds(
      (const __attribute__((address_space(1))) unsigned int*)g,
      (__attribute__((address_space(3))) unsigned int*)l, 16, 0, 0);
}

// ---------------------------------------------------------------------------
// Kernel 1: partition scan (verified R1-R4).
// ---------------------------------------------------------------------------
__global__ __launch_bounds__(256) void partition_kernel(
    const unsigned char* __restrict__ isctx, int* __restrict__ pos,
    int* __restrict__ ipos) {
  const int b = blockIdx.x;
  const int tid = threadIdx.x;
  const int wid = tid >> 6, lane = tid & 63;
  __shared__ int csum[4];
  __shared__ int waveTot[4];
  __shared__ int strideSh;

  int cnt = 0;
  for (int i = 0; i < 32; ++i) cnt += (isctx[tid * 32 + i] != 0);
  for (int off = 32; off; off >>= 1) cnt += __shfl_down(cnt, off, 64);
  if (lane == 0) csum[wid] = cnt;
  __syncthreads();
  if (tid == 0) {
    int t = csum[0] + csum[1] + csum[2] + csum[3];
    strideSh = (t > 2048) ? 1 : ((t > 768) ? 4 : 8);
  }
  __syncthreads();
  const int stride = strideSh;

  const unsigned char* base = isctx + (size_t)b * K_ * stride;
  int f[8];
  int s = 0;
  for (int i = 0; i < 8; ++i) {
    f[i] = base[(size_t)(tid * 8 + i) * stride] != 0;
    s += f[i];
  }
  int inc = s;
  for (int off = 1; off < 64; off <<= 1) {
    int v = __shfl_up(inc, off, 64);
    if (lane >= off) inc += v;
  }
  if (lane == 63) waveTot[wid] = inc;
  __syncthreads();
  int wOff = 0;
  for (int w = 0; w < wid; ++w) wOff += waveTot[w];
  int run = wOff + inc - s;
  for (int i = 0; i < 8; ++i) {
    int k = tid * 8 + i;
    int p;
    if (f[i]) {
      p = run;
      run++;
    } else {
      p = NCTX_ + k - run;
    }
    pos[b * K_ + k] = p;
    ipos[b * K_ + p] = k;
  }
}

// ---------------------------------------------------------------------------
// Kernel 2: RoPE + permute-gather -> f16 token buffer.
// ---------------------------------------------------------------------------
__global__ __launch_bounds__(256) void rope_kernel(
    const float* __restrict__ x, const float* __restrict__ coords,
    const float* __restrict__ cache, const int* __restrict__ ipos,
    f16* __restrict__ tok) {
  const int row = blockIdx.x;
  const int b = row >> 11;
  const int r = row & (K_ - 1);
  const int k = ipos[row];
  const int t = threadIdx.x;

  const float cy = coords[(size_t)(b * K_ + k) * 2 + 0];
  const float cx = coords[(size_t)(b * K_ + k) * 2 + 1];
  const int ypos = (int)fminf(fmaxf(cy / 224.0f * 1023.0f, 0.0f), 1023.0f);
  const int xpos = (int)fminf(fmaxf(cx / 224.0f * 1023.0f, 0.0f), 1023.0f);

  const float4 v = ((const float4*)(x + ((size_t)b * K_ + k) * D_))[t];
  const int e = 4 * t;
  const float* crow;
  int coff;
  if (e < 512) {
    crow = cache + (size_t)xpos * 512;
    coff = e;
  } else {
    crow = cache + (size_t)ypos * 512;
    coff = e - 512;
  }
  const float4 cs = *(const float4*)(crow + coff);
  float o[4];
  o[0] = v.x * cs.x - v.y * cs.y;
  o[1] = v.x * cs.y + v.y * cs.x;
  o[2] = v.z * cs.z - v.w * cs.w;
  o[3] = v.z * cs.w + v.w * cs.z;
  U4 h;
#pragma unroll
  for (int i = 0; i < 4; ++i) h.h[i] = (f16)o[i];
  ((ushort4*)(tok + ((size_t)b * K_ + r) * D_))[t] = h.u;
}

// ---------------------------------------------------------------------------
// Kernel 3: all weights fp32 -> f16, concatenated:
// [0,3M) ctx_in | [3M,5M) tgt_in kv | [5M,6M) tgt_in q | [6M,7M) ctx_out |
// [7M,8M) tgt_out   (M = 1048576 floats)
// ---------------------------------------------------------------------------
__global__ __launch_bounds__(256) void cvt_all(
    const float* __restrict__ ctx_in_w, const float* __restrict__ tgt_in_w,
    const float* __restrict__ ctx_out_w, const float* __restrict__ tgt_out_w,
    f16* __restrict__ dst) {
  const int i4 = blockIdx.x * 256 + threadIdx.x;  // 0..2097151
  const int f = i4 * 4;
  const float* src;
  if (f < 3145728) src = ctx_in_w + f;
  else if (f < 5242880) src = tgt_in_w + (f - 3145728 + 1048576);
  else if (f < 6291456) src = tgt_in_w + (f - 5242880);
  else if (f < 7340032) src = ctx_out_w + (f - 6291456);
  else src = tgt_out_w + (f - 7340032);
  const float4 v = *(const float4*)src;
  U4 u;
  u.h[0] = (f16)v.x;
  u.h[1] = (f16)v.y;
  u.h[2] = (f16)v.z;
  u.h[3] = (f16)v.w;
  ((ushort4*)dst)[i4] = u.u;
}

// ---------------------------------------------------------------------------
// GEMM core v3 (verified R3): coalesced staging (8-lane contiguous 128-B row
// segments), row-major [128][64] LDS with both-sides XOR swizzle, BK=64,
// double-buffered, counted vmcnt(8). gemm_proj 120 -> 75.8us, conflicts 0.
// ---------------------------------------------------------------------------
#define GEMM_PRE(AP, WP, Kd)                                                  \
  const int rb_ = wave * 8 + (lane >> 3);         /* row 0..31 (j adds 32) */ \
  const int kk_ = ((lane & 7) ^ (lane >> 3)) * 8; /* pre-swizzled k-chunk */  \
  const f16* gA_ = (AP) + (size_t)rb_ * (Kd) + kk_;                           \
  const f16* gW_ = (WP) + (size_t)rb_ * (Kd) + kk_;                           \
  const int lA_ = wave * 8 * 64 + lane * 8; /* == row*64 + kkchunk*8 */

#define GEMM_STAGE(k0s, bb)                                                   \
  _Pragma("unroll") for (int j = 0; j < 4; ++j) {                             \
    gload16(gA_ + (size_t)j * 32 * Kd_ + (k0s), &lds[(bb) + j * 2048 + lA_]); \
    gload16(gW_ + (size_t)j * 32 * Kd_ + (k0s),                               \
            &lds[(bb) + 8192 + j * 2048 + lA_]);                              \
  }

#define GEMM_TILE(bb)                                                         \
  _Pragma("unroll") for (int kh = 0; kh < 2; ++kh) {                          \
    f16x8 af[4], wf[4];                                                       \
    _Pragma("unroll") for (int i = 0; i < 4; ++i) {                           \
      const int ca = ((kh * 4 + quad) ^ (m16 & 7)) * 8;                       \
      af[i] = *(const f16x8*)&lds[(bb) + (wm + i * 16 + m16) * 64 + ca];      \
      wf[i] =                                                                 \
          *(const f16x8*)&lds[(bb) + 8192 + (wn + i * 16 + m16) * 64 + ca];   \
    }                                                                         \
    _Pragma("unroll") for (int i = 0; i < 4; ++i)                             \
        _Pragma("unroll") for (int j = 0; j < 4; ++j)                         \
      acc[i][j] = __builtin_amdgcn_mfma_f32_16x16x32_f16(af[i], wf[j],        \
                                                         acc[i][j], 0, 0, 0); \
  }

#define GEMM_CORE(AP, WP, Kd)                                                 \
  f32x4 acc[4][4];                                                            \
  {                                                                           \
    const f32x4 z = {0.f, 0.f, 0.f, 0.f};                                     \
    for (int i = 0; i < 4; ++i)                                               \
      for (int j = 0; j < 4; ++j) acc[i][j] = z;                              \
  }                                                                           \
  const int Kd_ = (Kd);                                                       \
  GEMM_PRE(AP, WP, Kd_)                                                       \
  GEMM_STAGE(0, 0)                                                            \
  for (int t = 0; t < Kd_ / 64; ++t) {                                        \
    const int cb = (t & 1) * 16384;                                           \
    if (t + 1 < Kd_ / 64) {                                                   \
      GEMM_STAGE((t + 1) * 64, ((t + 1) & 1) * 16384)                         \
      asm volatile("s_waitcnt vmcnt(8)" ::: "memory");                        \
    } else {                                                                  \
      asm volatile("s_waitcnt vmcnt(0)" ::: "memory");                        \
    }                                                                         \
    __builtin_amdgcn_s_barrier();                                             \
    asm volatile("" ::: "memory");                                            \
    GEMM_TILE(cb)                                                             \
    asm volatile("" ::: "memory");                                            \
    __builtin_amdgcn_s_barrier();                                             \
  }

// ---------------------------------------------------------------------------
// Kernel 4: merged projection GEMM. grid (48, 8, 4):
//   nb < 40: ctx rows x [ctx QK (2048) | ctx V (1024) | tgt K (1024) |
//            tgt V (1024)] -> qkvc / vtc^T / kvt / vtt^T
//   nb >= 40: tgt rows x tgt_in Q (1024) -> qt
// V strips written TRANSPOSED directly in the epilogue (verified R7).
// ---------------------------------------------------------------------------
__global__ __launch_bounds__(256, 2) void gemm_proj(
    const f16* __restrict__ tok, const f16* __restrict__ wcat,
    const float* __restrict__ ctx_in_b, const float* __restrict__ tgt_in_b,
    f16* __restrict__ qkvc, f16* __restrict__ kvt, f16* __restrict__ qt,
    f16* __restrict__ vtc, f16* __restrict__ vtt) {
  __shared__ f16 lds[32768];
  const int tid = threadIdx.x;
  const int wave = tid >> 6, lane = tid & 63;
  const int quad = lane >> 4, m16 = lane & 15;
  const int nb = blockIdx.x, mb = blockIdx.y, b = blockIdx.z;
  const int wm = (wave & 1) << 6, wn = (wave >> 1) << 6;
  const int m0 = mb * 128;
  const bool isQ = nb >= 40;
  const int n0 = isQ ? (nb - 40) * 128 : nb * 128;
  const f16* AP = tok + (size_t)b * K_ * D_ +
                  (isQ ? (size_t)NCTX_ * D_ : (size_t)0) + (size_t)m0 * D_;
  const f16* WP = wcat + (isQ ? (size_t)5242880 : (size_t)0) +
                  (size_t)n0 * D_;

  GEMM_CORE(AP, WP, D_)

#pragma unroll
  for (int j = 0; j < 4; ++j) {
    const int col = n0 + wn + j * 16 + m16;
    if (isQ) {
      const float bv = tgt_in_b[col];
      f16* dst = qt + (size_t)b * NCTX_ * 1024;
#pragma unroll
      for (int i = 0; i < 4; ++i) {
        const int mr = m0 + wm + i * 16 + quad * 4;
#pragma unroll
        for (int r = 0; r < 4; ++r)
          dst[(size_t)(mr + r) * 1024 + col] = (f16)(acc[i][j][r] + bv);
      }
    } else if (col < 2048) {
      // ctx Q,K -> qkvc (ld 2048)
      const float bv = ctx_in_b[col];
      f16* dst = qkvc + (size_t)b * NCTX_ * 2048;
#pragma unroll
      for (int i = 0; i < 4; ++i) {
        const int mr = m0 + wm + i * 16 + quad * 4;
#pragma unroll
        for (int r = 0; r < 4; ++r)
          dst[(size_t)(mr + r) * 2048 + col] = (f16)(acc[i][j][r] + bv);
      }
    } else if (col >= 3072 && col < 4096) {
      // tgt K -> kvt (ld 1024)
      const float bv = tgt_in_b[D_ + col - 3072];
      f16* dst = kvt + (size_t)b * NCTX_ * 1024;
      const int dcol = col - 3072;
#pragma unroll
      for (int i = 0; i < 4; ++i) {
        const int mr = m0 + wm + i * 16 + quad * 4;
#pragma unroll
        for (int r = 0; r < 4; ++r)
          dst[(size_t)(mr + r) * 1024 + dcol] = (f16)(acc[i][j][r] + bv);
      }
    } else {
      // V (ctx: 2048..3071 -> vtc; tgt: 4096..5119 -> vtt), transposed.
      const bool isCtxV = col < 3072;
      const int hd = isCtxV ? (col - 2048) : (col - 4096);  // h*64 + d
      const float bv = isCtxV ? ctx_in_b[col] : tgt_in_b[D_ + col - 3072];
      f16* dst = (isCtxV ? vtc : vtt) +
                 ((size_t)(b * H_ + (hd >> 6)) << 16) +
                 (size_t)(hd & 63) * 1024;
#pragma unroll
      for (int i = 0; i < 4; ++i) {
        const int mr = m0 + wm + i * 16 + quad * 4;  // kv base (mult of 4)
        P4 p4;
#pragma unroll
        for (int r = 0; r < 4; ++r) p4.h[r] = (f16)(acc[i][j][r] + bv);
        *(ushort4*)(dst + mr) = p4.u;
      }
    }
  }
}

// ---------------------------------------------------------------------------
// Kernel 5: merged output projections. grid (8, 8, 8): b = z&3, sel = z>>2.
// ---------------------------------------------------------------------------
__global__ __launch_bounds__(256, 2) void gemm_out(
    const f16* __restrict__ Atok, const f16* __restrict__ Wbase,
    const float* __restrict__ bias_ctx, const float* __restrict__ bias_tgt,
    const int* __restrict__ ipos, float* __restrict__ out) {
  __shared__ f16 lds[32768];
  const int tid = threadIdx.x;
  const int wave = tid >> 6, lane = tid & 63;
  const int quad = lane >> 4, m16 = lane & 15;
  const int n0 = blockIdx.x * 128, m0 = blockIdx.y * 128;
  const int b = blockIdx.z & 3, sel = blockIdx.z >> 2;
  const int wm = (wave & 1) << 6, wn = (wave >> 1) << 6;
  const f16* AP = Atok + (size_t)b * K_ * D_ + (size_t)sel * NCTX_ * D_ +
                  (size_t)m0 * D_;
  const f16* WP = Wbase + (size_t)sel * 1048576 + (size_t)n0 * D_;
  const float* bias = sel ? bias_tgt : bias_ctx;

  GEMM_CORE(AP, WP, D_)

#pragma unroll
  for (int j = 0; j < 4; ++j) {
    const int col = n0 + wn + j * 16 + m16;
    const float bv = bias[col];
#pragma unroll
    for (int i = 0; i < 4; ++i) {
      const int mr = m0 + wm + i * 16 + quad * 4;
#pragma unroll
      for (int r = 0; r < 4; ++r) {
        const int orow = ipos[b * K_ + sel * NCTX_ + mr + r];
        out[(size_t)b * K_ * D_ + (size_t)orow * D_ + col] =
            acc[i][j][r] + bv;
      }
    }
  }
}

// ---------------------------------------------------------------------------
// Kernel 7: MFMA flash attention v7 — KVBLK 64 -> 128 (8 kt iterations).
// R9 post-mortem: attn time invariant (75.4us) across memory/occupancy
// changes -> bound by per-kt fixed costs (barriers phase-locking 8 waves,
// serial shfl chains, defer checks). This round halves ALL of them:
//   - 8 kt x 128-kv tiles, built from TWO stacked verified [64][64]
//     sub-tiles per K/V tile (all sub-tile math byte-identical to R9).
//   - Full K/V double-buffer (2 x 16KB each) -> ONE barrier per kt
//     (barrier A of kt+1 orders all reads of buf before kt+2 overwrites).
//     Barriers/block: 33 -> 9. shfl chains: 64 -> 32. defer: 16 -> 8.
//   - PV in two 64-kv halves reusing the wave-private 1KB P buffer
//     (wave-local DS ordering + aliasing keeps write-after-read safe).
//   - LDS = QP 16K + K 32K + V 32K = 80KB -> 2 blocks/CU (= measured
//     effective occupancy of R9, so no TLP loss).
// XCD co-location decode kept (FETCH 139 -> 24.6 MB, verified R9).
// ---------------------------------------------------------------------------
__global__ __launch_bounds__(512) void attn_mfma(
    const f16* __restrict__ qkvc, const f16* __restrict__ kvt,
    const f16* __restrict__ qt, const f16* __restrict__ vtc,
    const f16* __restrict__ vtt, f16* __restrict__ O) {
  __shared__ f16 QP[8192];      // 128 x 64 Q staging; reused as P per-wave
  __shared__ f16 KB[2][8192];   // K dbuf: [buf][sub*4096 + row*64 + col]
  __shared__ f16 VB[2][8192];   // V dbuf (d-major sub-tiles)
  const int tid = threadIdx.x, wave = tid >> 6, lane = tid & 63;
  const int quad = lane >> 4, m16 = lane & 15;

  // XCD co-location decode: id = (g%8) + 8*j + 64*(g/8), g = (h,z) pair.
  const int id = blockIdx.x;
  const int xcd = id & 7;
  const int t_ = id >> 3;
  const int j_ = t_ & 7;                 // q-block 0..7
  const int g = ((t_ >> 3) << 3) + xcd;  // 0..127
  const int h = g & 15;
  const int zz = g >> 4;
  const int b = zz & 3;
  const bool isCtx = zz < 4;
  const int q0 = j_ * 128;

  const f16* Qb;
  const f16* Kb;
  int ld;
  if (isCtx) {
    Qb = qkvc + (size_t)b * NCTX_ * 2048 + h * 64;
    Kb = Qb + 1024;
    ld = 2048;
  } else {
    Qb = qt + (size_t)b * NCTX_ * 1024 + h * 64;
    Kb = kvt + (size_t)b * NCTX_ * 1024 + h * 64;
    ld = 1024;
  }
  const f16* Vb = (isCtx ? vtc : vtt) + ((size_t)(b * H_ + h) << 16);
  f16* Ob = O + (size_t)b * K_ * D_ + (isCtx ? 0 : (size_t)NCTX_ * D_);

  // Coalesced staging geometry (512 threads): row = tid>>3 (0..63),
  // chunk slot = tid&7, source chunk pre-swizzled by ^(row&7).
  const int rowS = tid >> 3;                     // 0..63
  const int kkc = ((tid & 7) ^ (rowS & 7)) * 8;  // pre-swizzled source chunk
  const int lB = tid * 8;                        // linear LDS dest (f16)

  // Prologue: Q (2 loads), then K[0]/V[0] (2 sub-tiles each).
#pragma unroll
  for (int j = 0; j < 2; ++j)
    gload16(Qb + (size_t)(q0 + j * 64 + rowS) * ld + kkc, &QP[j * 4096 + lB]);
#pragma unroll
  for (int j = 0; j < 2; ++j) {
    gload16(Kb + (size_t)(j * 64 + rowS) * ld + kkc, &KB[0][j * 4096 + lB]);
    gload16(Vb + (size_t)rowS * 1024 + j * 64 + kkc, &VB[0][j * 4096 + lB]);
  }

  float m_run = -1e30f, l_run = 0.f;
  f32x4 Oa[4];
  const f32x4 z = {0.f, 0.f, 0.f, 0.f};
#pragma unroll
  for (int j = 0; j < 4; ++j) Oa[j] = z;

  // Wait own Q loads (oldest 2 of 6 outstanding), barrier -> all Q in.
  asm volatile("s_waitcnt vmcnt(4)" ::: "memory");
  __builtin_amdgcn_s_barrier();

  // Hoisted Q fragments (B-operand: n = q = m16); wave owns rows
  // [wave*16, wave*16+16).
  const int c0 = (quad ^ (m16 & 7)) * 8;
  const int c1 = ((quad + 4) ^ (m16 & 7)) * 8;
  const f16x8 qf0 = *(const f16x8*)&QP[(wave * 16 + m16) * 64 + c0];
  const f16x8 qf1 = *(const f16x8*)&QP[(wave * 16 + m16) * 64 + c1];

  // Wave-private P tile (16 q x 64 kv) overlays this wave's own Q rows;
  // reused for both PV halves within a kt (wave-local DS ordering).
  f16* Pw = QP + wave * 1024;

  for (int kt = 0; kt < 8; ++kt) {
    const int cur = kt & 1;

    // Barrier A (the only barrier per kt): own tile-kt loads drained, all
    // waves arrived -> K[kt]/V[kt] fully in LDS; also orders all waves'
    // reads of buf[cur^1] (tile kt-1) before the stage below overwrites it.
    asm volatile("s_waitcnt vmcnt(0)" ::: "memory");
    __builtin_amdgcn_s_barrier();
    asm volatile("" ::: "memory");
    if (kt < 7) {
#pragma unroll
      for (int j = 0; j < 2; ++j) {
        gload16(Kb + (size_t)((kt + 1) * 128 + j * 64 + rowS) * ld + kkc,
                &KB[cur ^ 1][j * 4096 + lB]);
        gload16(Vb + (size_t)rowS * 1024 + (kt + 1) * 128 + j * 64 + kkc,
                &VB[cur ^ 1][j * 4096 + lB]);
      }
    }

    // Swapped QK^T over 128 kv: S[jn] covers kv = jn*16 + quad*4 + r.
    f32x4 S[8];
    __builtin_amdgcn_s_setprio(1);
#pragma unroll
    for (int jn = 0; jn < 8; ++jn) {
      S[jn] = z;
      const f16x8 kf0 = *(const f16x8*)&KB[cur][(jn >> 2) * 4096 +
                                               ((jn & 3) * 16 + m16) * 64 +
                                               c0];
      const f16x8 kf1 = *(const f16x8*)&KB[cur][(jn >> 2) * 4096 +
                                               ((jn & 3) * 16 + m16) * 64 +
                                               c1];
      S[jn] = __builtin_amdgcn_mfma_f32_16x16x32_f16(kf0, qf0, S[jn], 0, 0, 0);
      S[jn] = __builtin_amdgcn_mfma_f32_16x16x32_f16(kf1, qf1, S[jn], 0, 0, 0);
    }
    __builtin_amdgcn_s_setprio(0);

    // Row max over 128 kv: 31 in-lane fmax + 2 shfl_xor.
    float mv[4];
#pragma unroll
    for (int r = 0; r < 4; ++r) {
      const float a0 = fmaxf(fmaxf(S[0][r], S[1][r]), fmaxf(S[2][r], S[3][r]));
      const float a1 = fmaxf(fmaxf(S[4][r], S[5][r]), fmaxf(S[6][r], S[7][r]));
      mv[r] = fmaxf(a0, a1);
    }
    float mx = fmaxf(fmaxf(mv[0], mv[1]), fmaxf(mv[2], mv[3]));
    mx = fmaxf(mx, __shfl_xor(mx, 16, 64));
    mx = fmaxf(mx, __shfl_xor(mx, 32, 64));
    mx *= 0.125f;

    // EXACT defer-rescale: if no lane's max grew, al == 1 -> skip rescale.
    const bool grow = !__all(mx <= m_run);
    float al = 1.f;
    if (grow) {
      const float mnew = fmaxf(m_run, mx);
      al = __expf(m_run - mnew);
      m_run = mnew;
    }

    // P = exp(S*0.125 - m_run) for all 128 kv (stored back into S).
    float rs = 0.f;
#pragma unroll
    for (int jn = 0; jn < 8; ++jn)
#pragma unroll
      for (int r = 0; r < 4; ++r) {
        const float p = __expf(__builtin_fmaf(S[jn][r], 0.125f, -m_run));
        rs += p;
        S[jn][r] = p;
      }
    rs += __shfl_xor(rs, 16, 64);
    rs += __shfl_xor(rs, 32, 64);

    if (grow) {
      l_run = l_run * al + rs;
      // Broadcast al into the PV output domain q = quad*4 + r.
      float alq[4];
#pragma unroll
      for (int r = 0; r < 4; ++r) alq[r] = __shfl(al, quad * 4 + r, 64);
#pragma unroll
      for (int j = 0; j < 4; ++j) {
        Oa[j][0] *= alq[0];
        Oa[j][1] *= alq[1];
        Oa[j][2] *= alq[2];
        Oa[j][3] *= alq[3];
      }
    } else {
      l_run += rs;
    }

    // PV in two 64-kv halves; each half reuses the verified 64x64 path.
#pragma unroll
    for (int hf = 0; hf < 2; ++hf) {
      // Pack P half -> one b64 per j2 (swizzled), wave-private buffer.
#pragma unroll
      for (int j2 = 0; j2 < 4; ++j2) {
        const int jn = hf * 4 + j2;
        P4 p4;
#pragma unroll
        for (int r = 0; r < 4; ++r) p4.h[r] = (f16)S[jn][r];
        *(ushort4*)&Pw[m16 * 64 + (((j2 * 2 + (quad >> 1)) ^ (m16 & 7)) * 8) +
                       (quad & 1) * 4] = p4.u;
      }
      const f16x8 pf0 = *(const f16x8*)&Pw[m16 * 64 + c0];
      const f16x8 pf1 = *(const f16x8*)&Pw[m16 * 64 + c1];
      __builtin_amdgcn_s_setprio(1);
#pragma unroll
      for (int jd = 0; jd < 4; ++jd) {
        const f16x8 vf0 = *(const f16x8*)&VB[cur][hf * 4096 +
                                                 (jd * 16 + m16) * 64 + c0];
        const f16x8 vf1 = *(const f16x8*)&VB[cur][hf * 4096 +
                                                 (jd * 16 + m16) * 64 + c1];
        Oa[jd] =
            __builtin_amdgcn_mfma_f32_16x16x32_f16(pf0, vf0, Oa[jd], 0, 0, 0);
        Oa[jd] =
            __builtin_amdgcn_mfma_f32_16x16x32_f16(pf1, vf1, Oa[jd], 0, 0, 0);
      }
      __builtin_amdgcn_s_setprio(0);
    }
  }

  // l broadcast into output domain, then scale + store.
  float lq[4];
#pragma unroll
  for (int r = 0; r < 4; ++r) lq[r] = 1.0f / __shfl(l_run, quad * 4 + r, 64);
#pragma unroll
  for (int jd = 0; jd < 4; ++jd)
#pragma unroll
    for (int r = 0; r < 4; ++r) {
      const float v = Oa[jd][r] * lq[r];
      const size_t off = (size_t)(q0 + wave * 16 + quad * 4 + r) * D_ +
                         h * 64 + jd * 16 + m16;
      Ob[off] = (f16)v;
    }
}

// ---------------------------------------------------------------------------
extern "C" void kernel_launch(void* const* d_in, const int* in_sizes, int n_in,
                              void* d_out, int out_size, void* d_ws,
                              size_t ws_size, hipStream_t stream) {
  const float* x = (const float*)d_in[0];
  const float* coords = (const float*)d_in[1];
  const unsigned char* isctx = (const unsigned char*)d_in[2];
  const float* rope = (const float*)d_in[3];
  const float* ctx_in_w = (const float*)d_in[4];
  const float* ctx_in_b = (const float*)d_in[5];
  const float* ctx_out_w = (const float*)d_in[6];
  const float* ctx_out_b = (const float*)d_in[7];
  const float* tgt_in_w = (const float*)d_in[8];
  const float* tgt_in_b = (const float*)d_in[9];
  const float* tgt_out_w = (const float*)d_in[10];
  const float* tgt_out_b = (const float*)d_in[11];
  float* out = (float*)d_out;

  // ws layout (f16 units): tok 8M | wcat 8M | qkvc 8M (ctx QK, ld2048) |
  // kvt 4M (tgt K) | qt 4M | vtc 4M | vtt 4M | pos/ipos ints  (= 80 MB)
  f16* ws = (f16*)d_ws;
  f16* tok = ws;
  f16* wcat = tok + 8388608;
  f16* qkvc = wcat + 8388608;
  f16* kvt = qkvc + 8388608;
  f16* qt = kvt + 4194304;
  f16* vtc = qt + 4194304;
  f16* vtt = vtc + 4194304;
  int* pos = (int*)(vtt + 4194304);
  int* ipos = pos + B_ * K_;

  partition_kernel<<<B_, 256, 0, stream>>>(isctx, pos, ipos);
  cvt_all<<<8192, 256, 0, stream>>>(ctx_in_w, tgt_in_w, ctx_out_w, tgt_out_w,
                                    wcat);
  rope_kernel<<<B_ * K_, 256, 0, stream>>>(x, coords, rope, ipos, tok);

  // Merged projection: ctx QK + ctx V^T + tgt K + tgt V^T + tgt Q.
  gemm_proj<<<dim3(48, 8, B_), 256, 0, stream>>>(
      tok, wcat, ctx_in_b, tgt_in_b, qkvc, kvt, qt, vtc, vtt);

  // Merged ctx+tgt flash attention, 1-D grid with XCD co-location decode.
  attn_mfma<<<dim3(1024, 1, 1), 512, 0, stream>>>(qkvc, kvt, qt, vtc, vtt,
                                                  tok);

  // Merged output projections (fp32, scattered to original order)
  gemm_out<<<dim3(8, 8, 2 * B_), 256, 0, stream>>>(
      tok, wcat + 6291456, ctx_out_b, tgt_out_b, ipos, out);
}